// Round 12
// baseline (36.809 us; speedup 1.0000x reference)
//
#include <hip/hip_runtime.h>
#include <hip/hip_bf16.h>
#include <math.h>

typedef float  f32x4  __attribute__((ext_vector_type(4)));
typedef short  s16x4  __attribute__((ext_vector_type(4)));
typedef short  s16x8  __attribute__((ext_vector_type(8)));
typedef unsigned short u16;

__device__ inline u16 f2b(float f) {
    __hip_bfloat16 h = __float2bfloat16(f);
    return *reinterpret_cast<u16*>(&h);
}
__device__ inline float b2f(u16 v) {
    return __uint_as_float(((unsigned)v) << 16);
}

// ---------------------------------------------------------------------------
// K0: prep (weights only, 192 blocks): transpose-cast -> Wt [1024][512] bf16
// (rows 0-511 Wq^T | 512-767 Wk^T | 768-1023 Wv^T), Wot [512][512] = Wo^T.
// ---------------------------------------------------------------------------
__global__ __launch_bounds__(256) void prep(
    const float* __restrict__ Wq, const float* __restrict__ Wk,
    const float* __restrict__ Wv, const float* __restrict__ Wo,
    u16* __restrict__ Wt, u16* __restrict__ Wot)
{
    const int tid = threadIdx.x, bid = blockIdx.x;
    __shared__ u16 Tsh[64][72];
    const float* src; u16* dst; int N, base, kt, nt;
    if (bid < 64)       { src = Wq; dst = Wt;  N = 512; base = 0;   kt = bid >> 3;       nt = bid & 7; }
    else if (bid < 96)  { src = Wk; dst = Wt;  N = 256; base = 512; kt = (bid-64) >> 2;  nt = (bid-64) & 3; }
    else if (bid < 128) { src = Wv; dst = Wt;  N = 256; base = 768; kt = (bid-96) >> 2;  nt = (bid-96) & 3; }
    else                { src = Wo; dst = Wot; N = 512; base = 0;   kt = (bid-128) >> 3; nt = (bid-128) & 7; }
    const int k0 = kt * 64, n0 = nt * 64;
    const int r = tid >> 2, c0 = (tid & 3) * 16;
#pragma unroll
    for (int j = 0; j < 4; ++j) {
        float4 v = *(const float4*)(src + (size_t)(k0 + r) * N + n0 + c0 + j * 4);
        Tsh[c0 + j*4 + 0][r] = f2b(v.x);
        Tsh[c0 + j*4 + 1][r] = f2b(v.y);
        Tsh[c0 + j*4 + 2][r] = f2b(v.z);
        Tsh[c0 + j*4 + 3][r] = f2b(v.w);
    }
    __syncthreads();
    const int n = tid >> 2, kc = (tid & 3) * 16;
    u16* op = dst + (size_t)(base + n0 + n) * 512 + k0 + kc;
    *(s16x8*)(op)     = *(const s16x8*)&Tsh[n][kc];
    *(s16x8*)(op + 8) = *(const s16x8*)&Tsh[n][kc + 8];
}

// ---------------------------------------------------------------------------
// K1: QKV GEMM, A staged directly from x f32 (vectorized row-major loads +
// in-staging cast; converts hide under load latency). B = Wt bf16. Output
// qkvb bf16 [2048][1024]. 64x64 tile / 4 waves, 2-barrier loop.
// ---------------------------------------------------------------------------
__global__ __launch_bounds__(256) void qkv_gemm(const float* __restrict__ x,
    const u16* __restrict__ Bt, u16* __restrict__ C)
{
    __shared__ u16 Ash[64][72];
    __shared__ u16 Bsh[64][72];
    const int tid = threadIdx.x;
    const int m0b = blockIdx.y * 64, n0b = blockIdx.x * 64;
    const int lane = tid & 63, wv = tid >> 6;
    const int q = lane & 15, g = lane >> 4;
    const int wm = (wv & 1) * 32, wn = (wv >> 1) * 32;
    const int sr = tid >> 2, sc = (tid & 3) * 16;
    const float* xrow = x  + (size_t)(m0b + sr) * 512 + sc;
    const u16*   Brow = Bt + (size_t)(n0b + sr) * 512 + sc;
    f32x4 acc[2][2] = {{{0,0,0,0},{0,0,0,0}},{{0,0,0,0},{0,0,0,0}}};
    for (int k0 = 0; k0 < 512; k0 += 64) {
        float4 a0 = *(const float4*)(xrow + k0);
        float4 a1 = *(const float4*)(xrow + k0 + 4);
        float4 a2 = *(const float4*)(xrow + k0 + 8);
        float4 a3 = *(const float4*)(xrow + k0 + 12);
        s16x8 b0 = *(const s16x8*)(Brow + k0);
        s16x8 b1 = *(const s16x8*)(Brow + k0 + 8);
        s16x8 av0, av1;
        av0[0] = (short)f2b(a0.x); av0[1] = (short)f2b(a0.y);
        av0[2] = (short)f2b(a0.z); av0[3] = (short)f2b(a0.w);
        av0[4] = (short)f2b(a1.x); av0[5] = (short)f2b(a1.y);
        av0[6] = (short)f2b(a1.z); av0[7] = (short)f2b(a1.w);
        av1[0] = (short)f2b(a2.x); av1[1] = (short)f2b(a2.y);
        av1[2] = (short)f2b(a2.z); av1[3] = (short)f2b(a2.w);
        av1[4] = (short)f2b(a3.x); av1[5] = (short)f2b(a3.y);
        av1[6] = (short)f2b(a3.z); av1[7] = (short)f2b(a3.w);
        __syncthreads();
        *(s16x8*)&Ash[sr][sc]     = av0;
        *(s16x8*)&Ash[sr][sc + 8] = av1;
        *(s16x8*)&Bsh[sr][sc]     = b0;
        *(s16x8*)&Bsh[sr][sc + 8] = b1;
        __syncthreads();
#pragma unroll
        for (int kk = 0; kk < 64; kk += 32) {
            s16x8 af0 = *(const s16x8*)&Ash[wm + q][kk + g*8];
            s16x8 af1 = *(const s16x8*)&Ash[wm + 16 + q][kk + g*8];
            s16x8 bf0 = *(const s16x8*)&Bsh[wn + q][kk + g*8];
            s16x8 bf1 = *(const s16x8*)&Bsh[wn + 16 + q][kk + g*8];
            acc[0][0] = __builtin_amdgcn_mfma_f32_16x16x32_bf16(af0, bf0, acc[0][0], 0, 0, 0);
            acc[0][1] = __builtin_amdgcn_mfma_f32_16x16x32_bf16(af0, bf1, acc[0][1], 0, 0, 0);
            acc[1][0] = __builtin_amdgcn_mfma_f32_16x16x32_bf16(af1, bf0, acc[1][0], 0, 0, 0);
            acc[1][1] = __builtin_amdgcn_mfma_f32_16x16x32_bf16(af1, bf1, acc[1][1], 0, 0, 0);
        }
    }
#pragma unroll
    for (int mt = 0; mt < 2; ++mt)
#pragma unroll
        for (int nt = 0; nt < 2; ++nt)
#pragma unroll
            for (int r = 0; r < 4; ++r)
                C[(size_t)(m0b + wm + mt*16 + g*4 + r) * 1024 + n0b + wn + nt*16 + q] =
                    f2b(acc[mt][nt][r]);
}

// ---------------------------------------------------------------------------
// K2: GQA-merged sliding-window attention with fused RoPE+RMS.
// Block = (kvh, 32-query tile t0): K/V staged ONCE for BOTH q-heads sharing
// kvh. Wave wv -> head 2*kvh+(wv>>1), query subtile t0+(wv&1)*16.
// Window = 160 rows [t0-127, t0+32]. K roped+RMSed during staging; Q in-reg.
// Vt stride 162 (81 dwords, odd -> conflict-free PV reads).
// ---------------------------------------------------------------------------
__global__ __launch_bounds__(256) void swa_mfma(const u16* __restrict__ qkvb,
    const float* __restrict__ cosT, const float* __restrict__ sinT,
    const float* __restrict__ qw, const float* __restrict__ kw,
    u16* __restrict__ attb)
{
    __shared__ u16 Ksh[160][72];
    __shared__ u16 Vt[64][162];
    const int tid = threadIdx.x;
    const int kvh = blockIdx.y;
    const int t0 = blockIdx.x * 32;
    // ---- K staging + rope + rms: 160 rows x 8 chunks, 5 iters ----
    for (int i = 0; i < 5; ++i) {
        int idx = i * 256 + tid;
        int j = idx >> 3, e = idx & 7, d0 = e * 8;
        int kt = t0 - 127 + j;
        if (kt < 0 || kt >= 2048) {
            s16x8 z = {0,0,0,0,0,0,0,0};
            *(s16x8*)&Ksh[j][d0] = z;
        } else {
            s16x8 raw = *(const s16x8*)(qkvb + (size_t)kt * 1024 + 512 + kvh * 64 + d0);
            float kv[8], ov[8];
#pragma unroll
            for (int ii = 0; ii < 8; ++ii) kv[ii] = b2f((u16)raw[ii]);
#pragma unroll
            for (int ii = 0; ii < 8; ++ii) ov[ii] = __shfl_xor(kv[ii], 4);
            const float* cp = cosT + kt * 32 + (e & 3) * 8;
            const float* sp = sinT + kt * 32 + (e & 3) * 8;
            float4 c0 = *(const float4*)(cp), c1 = *(const float4*)(cp + 4);
            float4 s0 = *(const float4*)(sp), s1 = *(const float4*)(sp + 4);
            float cf[8] = {c0.x,c0.y,c0.z,c0.w,c1.x,c1.y,c1.z,c1.w};
            float sf[8] = {s0.x,s0.y,s0.z,s0.w,s1.x,s1.y,s1.z,s1.w};
            const bool lo = (e < 4);
            float r[8]; float ssl = 0.f;
#pragma unroll
            for (int ii = 0; ii < 8; ++ii) {
                r[ii] = lo ? (kv[ii]*cf[ii] - ov[ii]*sf[ii])
                           : (kv[ii]*cf[ii] + ov[ii]*sf[ii]);
                ssl += r[ii] * r[ii];
            }
            ssl += __shfl_xor(ssl, 1);
            ssl += __shfl_xor(ssl, 2);
            ssl += __shfl_xor(ssl, 4);
            float scale = rsqrtf(ssl * (1.0f / 64.0f) + 1e-6f);
            float4 w0 = *(const float4*)(kw + d0), w1 = *(const float4*)(kw + d0 + 4);
            float wf[8] = {w0.x,w0.y,w0.z,w0.w,w1.x,w1.y,w1.z,w1.w};
            s16x8 outv;
#pragma unroll
            for (int ii = 0; ii < 8; ++ii) outv[ii] = (short)f2b(r[ii] * scale * wf[ii]);
            *(s16x8*)&Ksh[j][d0] = outv;
        }
    }
    // ---- V staging (transposed): 160 cols, 5 iters ----
    for (int cch = 0; cch < 5; ++cch) {
        int w  = cch * 32 + (tid & 31);
        int d0 = (tid >> 5) * 8;
        int kt = t0 - 127 + w;
        s16x8 val = {0,0,0,0,0,0,0,0};
        if (kt >= 0 && kt < 2048)
            val = *(const s16x8*)(qkvb + (size_t)kt * 1024 + 768 + kvh * 64 + d0);
#pragma unroll
        for (int jj = 0; jj < 8; ++jj) Vt[d0 + jj][w] = ((const u16*)&val)[jj];
    }
    // ---- Q rope + rms (in-register, per wave's head/subtile) ----
    const int wv = tid >> 6, lane = tid & 63;
    const int q = lane & 15, g = lane >> 4;
    const int h  = 2 * kvh + (wv >> 1);
    const int tw = t0 + (wv & 1) * 16;
    const int jb = (wv & 1) * 16;     // wave's window base offset in LDS
    const int t = tw + q;
    s16x8 qf0, qf1;
    {
        const u16* qp = qkvb + (size_t)t * 1024 + h * 64;
        s16x8 q0r = *(const s16x8*)(qp + g * 8);
        s16x8 q1r = *(const s16x8*)(qp + 32 + g * 8);
        const float* cp = cosT + t * 32 + g * 8;
        const float* sp = sinT + t * 32 + g * 8;
        float4 c0 = *(const float4*)(cp), c1 = *(const float4*)(cp + 4);
        float4 s0 = *(const float4*)(sp), s1 = *(const float4*)(sp + 4);
        float cf[8] = {c0.x,c0.y,c0.z,c0.w,c1.x,c1.y,c1.z,c1.w};
        float sf[8] = {s0.x,s0.y,s0.z,s0.w,s1.x,s1.y,s1.z,s1.w};
        float rl[8], rh[8]; float ssl = 0.f;
#pragma unroll
        for (int ii = 0; ii < 8; ++ii) {
            float ql = b2f((u16)q0r[ii]), qh = b2f((u16)q1r[ii]);
            rl[ii] = ql * cf[ii] - qh * sf[ii];
            rh[ii] = qh * cf[ii] + ql * sf[ii];
            ssl += rl[ii]*rl[ii] + rh[ii]*rh[ii];
        }
        ssl += __shfl_xor(ssl, 16);
        ssl += __shfl_xor(ssl, 32);
        float scale = rsqrtf(ssl * (1.0f / 64.0f) + 1e-6f);
        float4 wl0 = *(const float4*)(qw + g * 8), wl1 = *(const float4*)(qw + g * 8 + 4);
        float4 wh0 = *(const float4*)(qw + 32 + g * 8), wh1 = *(const float4*)(qw + 32 + g * 8 + 4);
        float wlo[8] = {wl0.x,wl0.y,wl0.z,wl0.w,wl1.x,wl1.y,wl1.z,wl1.w};
        float whi[8] = {wh0.x,wh0.y,wh0.z,wh0.w,wh1.x,wh1.y,wh1.z,wh1.w};
#pragma unroll
        for (int ii = 0; ii < 8; ++ii) {
            qf0[ii] = (short)f2b(rl[ii] * scale * wlo[ii]);
            qf1[ii] = (short)f2b(rh[ii] * scale * whi[ii]);
        }
    }
    __syncthreads();
    // ---- QK^T -> softmax -> PV (verified math, per-wave tw/h/jb) ----
    float s[9][4];
    float mx = -INFINITY;
    for (int wt = 0; wt < 9; ++wt) {
        int ldsrow = jb + wt * 16 + q;
        s16x8 kf0 = *(const s16x8*)&Ksh[ldsrow][g * 8];
        s16x8 kf1 = *(const s16x8*)&Ksh[ldsrow][32 + g * 8];
        f32x4 accv = {0, 0, 0, 0};
        accv = __builtin_amdgcn_mfma_f32_16x16x32_bf16(kf0, qf0, accv, 0, 0, 0);
        accv = __builtin_amdgcn_mfma_f32_16x16x32_bf16(kf1, qf1, accv, 0, 0, 0);
#pragma unroll
        for (int r = 0; r < 4; ++r) {
            int woff = wt * 16 + g * 4 + r;
            int key  = tw - 127 + woff;
            bool ok = (woff >= q) && (woff <= q + 127) && (key >= 0);
            float sv = ok ? accv[r] * 0.125f : -INFINITY;
            s[wt][r] = sv;
            mx = fmaxf(mx, sv);
        }
    }
    mx = fmaxf(mx, __shfl_xor(mx, 16));
    mx = fmaxf(mx, __shfl_xor(mx, 32));
    float sum = 0.f;
    s16x4 pb[9];
    for (int wt = 0; wt < 9; ++wt) {
#pragma unroll
        for (int r = 0; r < 4; ++r) {
            float p = __expf(s[wt][r] - mx);
            sum += p;
            pb[wt][r] = (short)f2b(p);
        }
    }
    sum += __shfl_xor(sum, 16);
    sum += __shfl_xor(sum, 32);
    float inv = 1.0f / sum;
    f32x4 oacc[4];
#pragma unroll
    for (int dt = 0; dt < 4; ++dt) {
        f32x4 a = {0, 0, 0, 0};
        for (int wt = 0; wt < 9; ++wt) {
            int col = jb + wt * 16 + g * 4;
            s16x4 vf = *(const s16x4*)&Vt[dt * 16 + q][col];
            a = __builtin_amdgcn_mfma_f32_16x16x16bf16_1k(vf, pb[wt], a, 0, 0, 0);
        }
        oacc[dt] = a;
    }
    __syncthreads();
    float (*Osh)[16][68] = (float (*)[16][68])&Ksh[0][0];  // 17408 B < 23040 B
#pragma unroll
    for (int dt = 0; dt < 4; ++dt)
#pragma unroll
        for (int r = 0; r < 4; ++r)
            Osh[wv][q][dt * 16 + g * 4 + r] = oacc[dt][r] * inv;
    __syncthreads();
    const int qq = lane >> 2, dd0 = (lane & 3) * 16;
    u16* op = attb + (size_t)(tw + qq) * 512 + h * 64 + dd0;
#pragma unroll
    for (int jj = 0; jj < 4; ++jj) {
        float4 vvv = *(const float4*)&Osh[wv][qq][dd0 + jj * 4];
        ushort4 ov = { f2b(vvv.x), f2b(vvv.y), f2b(vvv.z), f2b(vvv.w) };
        *(ushort4*)(op + jj * 4) = ov;
    }
}

// ---------------------------------------------------------------------------
// K3: output projection. C f32 = attb bf16 @ Wot^T (pre-transposed bf16).
// Verified 2-barrier structure.
// ---------------------------------------------------------------------------
__global__ __launch_bounds__(256) void oproj(const u16* __restrict__ A,
    const u16* __restrict__ Bt, float* __restrict__ C)
{
    __shared__ u16 Ash[64][72];
    __shared__ u16 Bsh[64][72];
    const int tid = threadIdx.x;
    const int m0 = blockIdx.y * 64, n0 = blockIdx.x * 64;
    const int lane = tid & 63, wv = tid >> 6;
    const int q = lane & 15, g = lane >> 4;
    const int wm = (wv & 1) * 32, wn = (wv >> 1) * 32;
    const int sr = tid >> 2, sc = (tid & 3) * 16;
    f32x4 acc[2][2] = {{{0,0,0,0},{0,0,0,0}},{{0,0,0,0},{0,0,0,0}}};
    for (int k0 = 0; k0 < 512; k0 += 64) {
        s16x8 a0 = *(const s16x8*)(A  + (size_t)(m0 + sr) * 512 + k0 + sc);
        s16x8 a1 = *(const s16x8*)(A  + (size_t)(m0 + sr) * 512 + k0 + sc + 8);
        s16x8 b0 = *(const s16x8*)(Bt + (size_t)(n0 + sr) * 512 + k0 + sc);
        s16x8 b1 = *(const s16x8*)(Bt + (size_t)(n0 + sr) * 512 + k0 + sc + 8);
        __syncthreads();
        *(s16x8*)&Ash[sr][sc]     = a0;
        *(s16x8*)&Ash[sr][sc + 8] = a1;
        *(s16x8*)&Bsh[sr][sc]     = b0;
        *(s16x8*)&Bsh[sr][sc + 8] = b1;
        __syncthreads();
#pragma unroll
        for (int kk = 0; kk < 64; kk += 32) {
            s16x8 af0 = *(const s16x8*)&Ash[wm + q][kk + g*8];
            s16x8 af1 = *(const s16x8*)&Ash[wm + 16 + q][kk + g*8];
            s16x8 bf0 = *(const s16x8*)&Bsh[wn + q][kk + g*8];
            s16x8 bf1 = *(const s16x8*)&Bsh[wn + 16 + q][kk + g*8];
            acc[0][0] = __builtin_amdgcn_mfma_f32_16x16x32_bf16(af0, bf0, acc[0][0], 0, 0, 0);
            acc[0][1] = __builtin_amdgcn_mfma_f32_16x16x32_bf16(af0, bf1, acc[0][1], 0, 0, 0);
            acc[1][0] = __builtin_amdgcn_mfma_f32_16x16x32_bf16(af1, bf0, acc[1][0], 0, 0, 0);
            acc[1][1] = __builtin_amdgcn_mfma_f32_16x16x32_bf16(af1, bf1, acc[1][1], 0, 0, 0);
        }
    }
#pragma unroll
    for (int mt = 0; mt < 2; ++mt)
#pragma unroll
        for (int nt = 0; nt < 2; ++nt)
#pragma unroll
            for (int r = 0; r < 4; ++r)
                C[(size_t)(m0 + wm + mt*16 + g*4 + r) * 512 + n0 + wn + nt*16 + q] = acc[mt][nt][r];
}

// ---------------------------------------------------------------------------
// Workspace: Wt [1024*512 u16] | Wot [512*512] | qkvb [2048*1024] |
//            attb [2048*512]   ≈ 7.5 MB
// ---------------------------------------------------------------------------
extern "C" void kernel_launch(void* const* d_in, const int* in_sizes, int n_in,
                              void* d_out, int out_size, void* d_ws, size_t ws_size,
                              hipStream_t stream)
{
    const float* x    = (const float*)d_in[0];
    const float* Wq   = (const float*)d_in[1];
    const float* Wk   = (const float*)d_in[2];
    const float* Wv   = (const float*)d_in[3];
    const float* Wo   = (const float*)d_in[4];
    const float* qw   = (const float*)d_in[5];
    const float* kw   = (const float*)d_in[6];
    const float* cosT = (const float*)d_in[7];
    const float* sinT = (const float*)d_in[8];

    u16* ws   = (u16*)d_ws;
    u16* Wt   = ws;                               // 1024*512
    u16* Wot  = Wt   + (size_t)1024 * 512;        // 512*512
    u16* qkvb = Wot  + (size_t)512 * 512;         // 2048*1024
    u16* attb = qkvb + (size_t)2048 * 1024;       // 2048*512

    dim3 blk(256);
    hipLaunchKernelGGL(prep, dim3(192), blk, 0, stream, Wq, Wk, Wv, Wo, Wt, Wot);
    hipLaunchKernelGGL(qkv_gemm, dim3(16, 32), blk, 0, stream, x, Wt, qkvb);
    hipLaunchKernelGGL(swa_mfma, dim3(64, 4), blk, 0, stream,
                       qkvb, cosT, sinT, qw, kw, attb);
    hipLaunchKernelGGL(oproj, dim3(8, 32), blk, 0, stream, attb, Wot, (float*)d_out);
}

// Round 13
// 34.333 us; speedup vs baseline: 1.0721x; 1.0721x over previous
//
#include <hip/hip_runtime.h>
#include <hip/hip_bf16.h>
#include <math.h>

typedef float  f32x4  __attribute__((ext_vector_type(4)));
typedef short  s16x4  __attribute__((ext_vector_type(4)));
typedef short  s16x8  __attribute__((ext_vector_type(8)));
typedef unsigned short u16;

__device__ inline u16 f2b(float f) {
    __hip_bfloat16 h = __float2bfloat16(f);
    return *reinterpret_cast<u16*>(&h);
}
__device__ inline float b2f(u16 v) {
    return __uint_as_float(((unsigned)v) << 16);
}
__device__ inline void st_out(float* p, float v) { *p = v; }
__device__ inline void st_out(u16* p, float v)   { *p = f2b(v); }

// ---------------------------------------------------------------------------
// K0: prep. blocks 0-191: transpose-cast weights -> Wt [1024][512] bf16
// (rows 0-511 Wq^T | 512-767 Wk^T | 768-1023 Wv^T), Wot [512][512] = Wo^T.
// blocks 192-703: cast x -> xb bf16 (8 elems/thread, vectorized).
// The two groups run concurrently; x-cast is effectively free.
// ---------------------------------------------------------------------------
__global__ __launch_bounds__(256) void prep(const float* __restrict__ x,
    const float* __restrict__ Wq, const float* __restrict__ Wk,
    const float* __restrict__ Wv, const float* __restrict__ Wo,
    u16* __restrict__ xb, u16* __restrict__ Wt, u16* __restrict__ Wot)
{
    const int tid = threadIdx.x, bid = blockIdx.x;
    if (bid >= 192) {   // x cast
        int i = ((bid - 192) * 256 + tid) * 8;
        float4 v0 = *(const float4*)(x + i);
        float4 v1 = *(const float4*)(x + i + 4);
        ushort4 o0 = { f2b(v0.x), f2b(v0.y), f2b(v0.z), f2b(v0.w) };
        ushort4 o1 = { f2b(v1.x), f2b(v1.y), f2b(v1.z), f2b(v1.w) };
        *(ushort4*)(xb + i)     = o0;
        *(ushort4*)(xb + i + 4) = o1;
        return;
    }
    __shared__ u16 Tsh[64][72];
    const float* src; u16* dst; int N, base, kt, nt;
    if (bid < 64)       { src = Wq; dst = Wt;  N = 512; base = 0;   kt = bid >> 3;       nt = bid & 7; }
    else if (bid < 96)  { src = Wk; dst = Wt;  N = 256; base = 512; kt = (bid-64) >> 2;  nt = (bid-64) & 3; }
    else if (bid < 128) { src = Wv; dst = Wt;  N = 256; base = 768; kt = (bid-96) >> 2;  nt = (bid-96) & 3; }
    else                { src = Wo; dst = Wot; N = 512; base = 0;   kt = (bid-128) >> 3; nt = (bid-128) & 7; }
    const int k0 = kt * 64, n0 = nt * 64;
    const int r = tid >> 2, c0 = (tid & 3) * 16;
#pragma unroll
    for (int j = 0; j < 4; ++j) {
        float4 v = *(const float4*)(src + (size_t)(k0 + r) * N + n0 + c0 + j * 4);
        Tsh[c0 + j*4 + 0][r] = f2b(v.x);
        Tsh[c0 + j*4 + 1][r] = f2b(v.y);
        Tsh[c0 + j*4 + 2][r] = f2b(v.z);
        Tsh[c0 + j*4 + 3][r] = f2b(v.w);
    }
    __syncthreads();
    const int n = tid >> 2, kc = (tid & 3) * 16;
    u16* op = dst + (size_t)(base + n0 + n) * 512 + k0 + kc;
    *(s16x8*)(op)     = *(const s16x8*)&Tsh[n][kc];
    *(s16x8*)(op + 8) = *(const s16x8*)&Tsh[n][kc + 8];
}

// ---------------------------------------------------------------------------
// bf16 MFMA GEMM (verified R9/R11 fast path): C[M x N] OutT = A bf16 @ Bt
// bf16. 64x64 tile / 4 waves (32x32 each), BK=64, 2-barrier loop, pure
// s16x8 vector staging.
// ---------------------------------------------------------------------------
template<typename OutT>
__global__ __launch_bounds__(256) void gemm_mfma(const u16* __restrict__ A,
    const u16* __restrict__ Bt, OutT* __restrict__ C, int ldc)
{
    __shared__ u16 Ash[64][72];
    __shared__ u16 Bsh[64][72];
    const int tid = threadIdx.x;
    const int m0b = blockIdx.y * 64, n0b = blockIdx.x * 64;
    const int lane = tid & 63, wv = tid >> 6;
    const int q = lane & 15, g = lane >> 4;
    const int wm = (wv & 1) * 32, wn = (wv >> 1) * 32;
    const int sr = tid >> 2, sc = (tid & 3) * 16;
    f32x4 acc[2][2] = {{{0,0,0,0},{0,0,0,0}},{{0,0,0,0},{0,0,0,0}}};
    for (int k0 = 0; k0 < 512; k0 += 64) {
        s16x8 a0 = *(const s16x8*)(A  + (size_t)(m0b + sr) * 512 + k0 + sc);
        s16x8 a1 = *(const s16x8*)(A  + (size_t)(m0b + sr) * 512 + k0 + sc + 8);
        s16x8 b0 = *(const s16x8*)(Bt + (size_t)(n0b + sr) * 512 + k0 + sc);
        s16x8 b1 = *(const s16x8*)(Bt + (size_t)(n0b + sr) * 512 + k0 + sc + 8);
        __syncthreads();
        *(s16x8*)&Ash[sr][sc]     = a0;
        *(s16x8*)&Ash[sr][sc + 8] = a1;
        *(s16x8*)&Bsh[sr][sc]     = b0;
        *(s16x8*)&Bsh[sr][sc + 8] = b1;
        __syncthreads();
#pragma unroll
        for (int kk = 0; kk < 64; kk += 32) {
            s16x8 af0 = *(const s16x8*)&Ash[wm + q][kk + g*8];
            s16x8 af1 = *(const s16x8*)&Ash[wm + 16 + q][kk + g*8];
            s16x8 bf0 = *(const s16x8*)&Bsh[wn + q][kk + g*8];
            s16x8 bf1 = *(const s16x8*)&Bsh[wn + 16 + q][kk + g*8];
            acc[0][0] = __builtin_amdgcn_mfma_f32_16x16x32_bf16(af0, bf0, acc[0][0], 0, 0, 0);
            acc[0][1] = __builtin_amdgcn_mfma_f32_16x16x32_bf16(af0, bf1, acc[0][1], 0, 0, 0);
            acc[1][0] = __builtin_amdgcn_mfma_f32_16x16x32_bf16(af1, bf0, acc[1][0], 0, 0, 0);
            acc[1][1] = __builtin_amdgcn_mfma_f32_16x16x32_bf16(af1, bf1, acc[1][1], 0, 0, 0);
        }
    }
#pragma unroll
    for (int mt = 0; mt < 2; ++mt)
#pragma unroll
        for (int nt = 0; nt < 2; ++nt)
#pragma unroll
            for (int r = 0; r < 4; ++r)
                st_out(&C[(size_t)(m0b + wm + mt*16 + g*4 + r) * ldc + n0b + wn + nt*16 + q],
                       acc[mt][nt][r]);
}

// ---------------------------------------------------------------------------
// K2: GQA-merged sliding-window attention with fused RoPE+RMS (R12, kept).
// Block = (kvh, 32-query tile t0): K/V staged ONCE for BOTH q-heads sharing
// kvh. Wave wv -> head 2*kvh+(wv>>1), query subtile t0+(wv&1)*16.
// Window = 160 rows [t0-127, t0+32]. K roped+RMSed during staging; Q in-reg.
// Vt stride 162 (81 dwords, odd -> conflict-free PV reads).
// ---------------------------------------------------------------------------
__global__ __launch_bounds__(256) void swa_mfma(const u16* __restrict__ qkvb,
    const float* __restrict__ cosT, const float* __restrict__ sinT,
    const float* __restrict__ qw, const float* __restrict__ kw,
    u16* __restrict__ attb)
{
    __shared__ u16 Ksh[160][72];
    __shared__ u16 Vt[64][162];
    const int tid = threadIdx.x;
    const int kvh = blockIdx.y;
    const int t0 = blockIdx.x * 32;
    // ---- K staging + rope + rms: 160 rows x 8 chunks, 5 iters ----
    for (int i = 0; i < 5; ++i) {
        int idx = i * 256 + tid;
        int j = idx >> 3, e = idx & 7, d0 = e * 8;
        int kt = t0 - 127 + j;
        if (kt < 0 || kt >= 2048) {
            s16x8 z = {0,0,0,0,0,0,0,0};
            *(s16x8*)&Ksh[j][d0] = z;
        } else {
            s16x8 raw = *(const s16x8*)(qkvb + (size_t)kt * 1024 + 512 + kvh * 64 + d0);
            float kv[8], ov[8];
#pragma unroll
            for (int ii = 0; ii < 8; ++ii) kv[ii] = b2f((u16)raw[ii]);
#pragma unroll
            for (int ii = 0; ii < 8; ++ii) ov[ii] = __shfl_xor(kv[ii], 4);
            const float* cp = cosT + kt * 32 + (e & 3) * 8;
            const float* sp = sinT + kt * 32 + (e & 3) * 8;
            float4 c0 = *(const float4*)(cp), c1 = *(const float4*)(cp + 4);
            float4 s0 = *(const float4*)(sp), s1 = *(const float4*)(sp + 4);
            float cf[8] = {c0.x,c0.y,c0.z,c0.w,c1.x,c1.y,c1.z,c1.w};
            float sf[8] = {s0.x,s0.y,s0.z,s0.w,s1.x,s1.y,s1.z,s1.w};
            const bool lo = (e < 4);
            float r[8]; float ssl = 0.f;
#pragma unroll
            for (int ii = 0; ii < 8; ++ii) {
                r[ii] = lo ? (kv[ii]*cf[ii] - ov[ii]*sf[ii])
                           : (kv[ii]*cf[ii] + ov[ii]*sf[ii]);
                ssl += r[ii] * r[ii];
            }
            ssl += __shfl_xor(ssl, 1);
            ssl += __shfl_xor(ssl, 2);
            ssl += __shfl_xor(ssl, 4);
            float scale = rsqrtf(ssl * (1.0f / 64.0f) + 1e-6f);
            float4 w0 = *(const float4*)(kw + d0), w1 = *(const float4*)(kw + d0 + 4);
            float wf[8] = {w0.x,w0.y,w0.z,w0.w,w1.x,w1.y,w1.z,w1.w};
            s16x8 outv;
#pragma unroll
            for (int ii = 0; ii < 8; ++ii) outv[ii] = (short)f2b(r[ii] * scale * wf[ii]);
            *(s16x8*)&Ksh[j][d0] = outv;
        }
    }
    // ---- V staging (transposed): 160 cols, 5 iters ----
    for (int cch = 0; cch < 5; ++cch) {
        int w  = cch * 32 + (tid & 31);
        int d0 = (tid >> 5) * 8;
        int kt = t0 - 127 + w;
        s16x8 val = {0,0,0,0,0,0,0,0};
        if (kt >= 0 && kt < 2048)
            val = *(const s16x8*)(qkvb + (size_t)kt * 1024 + 768 + kvh * 64 + d0);
#pragma unroll
        for (int jj = 0; jj < 8; ++jj) Vt[d0 + jj][w] = ((const u16*)&val)[jj];
    }
    // ---- Q rope + rms (in-register, per wave's head/subtile) ----
    const int wv = tid >> 6, lane = tid & 63;
    const int q = lane & 15, g = lane >> 4;
    const int h  = 2 * kvh + (wv >> 1);
    const int tw = t0 + (wv & 1) * 16;
    const int jb = (wv & 1) * 16;     // wave's window base offset in LDS
    const int t = tw + q;
    s16x8 qf0, qf1;
    {
        const u16* qp = qkvb + (size_t)t * 1024 + h * 64;
        s16x8 q0r = *(const s16x8*)(qp + g * 8);
        s16x8 q1r = *(const s16x8*)(qp + 32 + g * 8);
        const float* cp = cosT + t * 32 + g * 8;
        const float* sp = sinT + t * 32 + g * 8;
        float4 c0 = *(const float4*)(cp), c1 = *(const float4*)(cp + 4);
        float4 s0 = *(const float4*)(sp), s1 = *(const float4*)(sp + 4);
        float cf[8] = {c0.x,c0.y,c0.z,c0.w,c1.x,c1.y,c1.z,c1.w};
        float sf[8] = {s0.x,s0.y,s0.z,s0.w,s1.x,s1.y,s1.z,s1.w};
        float rl[8], rh[8]; float ssl = 0.f;
#pragma unroll
        for (int ii = 0; ii < 8; ++ii) {
            float ql = b2f((u16)q0r[ii]), qh = b2f((u16)q1r[ii]);
            rl[ii] = ql * cf[ii] - qh * sf[ii];
            rh[ii] = qh * cf[ii] + ql * sf[ii];
            ssl += rl[ii]*rl[ii] + rh[ii]*rh[ii];
        }
        ssl += __shfl_xor(ssl, 16);
        ssl += __shfl_xor(ssl, 32);
        float scale = rsqrtf(ssl * (1.0f / 64.0f) + 1e-6f);
        float4 wl0 = *(const float4*)(qw + g * 8), wl1 = *(const float4*)(qw + g * 8 + 4);
        float4 wh0 = *(const float4*)(qw + 32 + g * 8), wh1 = *(const float4*)(qw + 32 + g * 8 + 4);
        float wlo[8] = {wl0.x,wl0.y,wl0.z,wl0.w,wl1.x,wl1.y,wl1.z,wl1.w};
        float whi[8] = {wh0.x,wh0.y,wh0.z,wh0.w,wh1.x,wh1.y,wh1.z,wh1.w};
#pragma unroll
        for (int ii = 0; ii < 8; ++ii) {
            qf0[ii] = (short)f2b(rl[ii] * scale * wlo[ii]);
            qf1[ii] = (short)f2b(rh[ii] * scale * whi[ii]);
        }
    }
    __syncthreads();
    // ---- QK^T -> softmax -> PV (verified math, per-wave tw/h/jb) ----
    float s[9][4];
    float mx = -INFINITY;
    for (int wt = 0; wt < 9; ++wt) {
        int ldsrow = jb + wt * 16 + q;
        s16x8 kf0 = *(const s16x8*)&Ksh[ldsrow][g * 8];
        s16x8 kf1 = *(const s16x8*)&Ksh[ldsrow][32 + g * 8];
        f32x4 accv = {0, 0, 0, 0};
        accv = __builtin_amdgcn_mfma_f32_16x16x32_bf16(kf0, qf0, accv, 0, 0, 0);
        accv = __builtin_amdgcn_mfma_f32_16x16x32_bf16(kf1, qf1, accv, 0, 0, 0);
#pragma unroll
        for (int r = 0; r < 4; ++r) {
            int woff = wt * 16 + g * 4 + r;
            int key  = tw - 127 + woff;
            bool ok = (woff >= q) && (woff <= q + 127) && (key >= 0);
            float sv = ok ? accv[r] * 0.125f : -INFINITY;
            s[wt][r] = sv;
            mx = fmaxf(mx, sv);
        }
    }
    mx = fmaxf(mx, __shfl_xor(mx, 16));
    mx = fmaxf(mx, __shfl_xor(mx, 32));
    float sum = 0.f;
    s16x4 pb[9];
    for (int wt = 0; wt < 9; ++wt) {
#pragma unroll
        for (int r = 0; r < 4; ++r) {
            float p = __expf(s[wt][r] - mx);
            sum += p;
            pb[wt][r] = (short)f2b(p);
        }
    }
    sum += __shfl_xor(sum, 16);
    sum += __shfl_xor(sum, 32);
    float inv = 1.0f / sum;
    f32x4 oacc[4];
#pragma unroll
    for (int dt = 0; dt < 4; ++dt) {
        f32x4 a = {0, 0, 0, 0};
        for (int wt = 0; wt < 9; ++wt) {
            int col = jb + wt * 16 + g * 4;
            s16x4 vf = *(const s16x4*)&Vt[dt * 16 + q][col];
            a = __builtin_amdgcn_mfma_f32_16x16x16bf16_1k(vf, pb[wt], a, 0, 0, 0);
        }
        oacc[dt] = a;
    }
    __syncthreads();
    float (*Osh)[16][68] = (float (*)[16][68])&Ksh[0][0];  // 17408 B < 23040 B
#pragma unroll
    for (int dt = 0; dt < 4; ++dt)
#pragma unroll
        for (int r = 0; r < 4; ++r)
            Osh[wv][q][dt * 16 + g * 4 + r] = oacc[dt][r] * inv;
    __syncthreads();
    const int qq = lane >> 2, dd0 = (lane & 3) * 16;
    u16* op = attb + (size_t)(tw + qq) * 512 + h * 64 + dd0;
#pragma unroll
    for (int jj = 0; jj < 4; ++jj) {
        float4 vvv = *(const float4*)&Osh[wv][qq][dd0 + jj * 4];
        ushort4 ov = { f2b(vvv.x), f2b(vvv.y), f2b(vvv.z), f2b(vvv.w) };
        *(ushort4*)(op + jj * 4) = ov;
    }
}

// ---------------------------------------------------------------------------
// Workspace: xb [2048*512 u16] | Wt [1024*512] | Wot [512*512] |
//            qkvb [2048*1024] | attb [2048*512]  ≈ 9.5 MB
// ---------------------------------------------------------------------------
extern "C" void kernel_launch(void* const* d_in, const int* in_sizes, int n_in,
                              void* d_out, int out_size, void* d_ws, size_t ws_size,
                              hipStream_t stream)
{
    const float* x    = (const float*)d_in[0];
    const float* Wq   = (const float*)d_in[1];
    const float* Wk   = (const float*)d_in[2];
    const float* Wv   = (const float*)d_in[3];
    const float* Wo   = (const float*)d_in[4];
    const float* qw   = (const float*)d_in[5];
    const float* kw   = (const float*)d_in[6];
    const float* cosT = (const float*)d_in[7];
    const float* sinT = (const float*)d_in[8];

    u16* ws   = (u16*)d_ws;
    u16* xb   = ws;                               // 2048*512
    u16* Wt   = xb   + (size_t)2048 * 512;        // 1024*512
    u16* Wot  = Wt   + (size_t)1024 * 512;        // 512*512
    u16* qkvb = Wot  + (size_t)512 * 512;         // 2048*1024
    u16* attb = qkvb + (size_t)2048 * 1024;       // 2048*512

    dim3 blk(256);
    hipLaunchKernelGGL(prep, dim3(704), blk, 0, stream, x, Wq, Wk, Wv, Wo, xb, Wt, Wot);
    hipLaunchKernelGGL((gemm_mfma<u16>), dim3(16, 32), blk, 0, stream, xb, Wt, qkvb, 1024);
    hipLaunchKernelGGL(swa_mfma, dim3(64, 4), blk, 0, stream,
                       qkvb, cosT, sinT, qw, kw, attb);
    hipLaunchKernelGGL((gemm_mfma<float>), dim3(8, 32), blk, 0, stream,
                       attb, Wot, (float*)d_out, 512);
}

// Round 14
// 34.192 us; speedup vs baseline: 1.0765x; 1.0041x over previous
//
#include <hip/hip_runtime.h>
#include <hip/hip_bf16.h>
#include <math.h>

typedef float  f32x4  __attribute__((ext_vector_type(4)));
typedef short  s16x4  __attribute__((ext_vector_type(4)));
typedef short  s16x8  __attribute__((ext_vector_type(8)));
typedef unsigned short u16;

__device__ inline u16 f2b(float f) {
    __hip_bfloat16 h = __float2bfloat16(f);
    return *reinterpret_cast<u16*>(&h);
}
__device__ inline float b2f(u16 v) {
    return __uint_as_float(((unsigned)v) << 16);
}
__device__ inline void st_out(float* p, float v) { *p = v; }
__device__ inline void st_out(u16* p, float v)   { *p = f2b(v); }

// async global->LDS, 16B per lane; LDS dest = uniform base + lane*16.
__device__ inline void gload16(const void* g, void* l) {
    __builtin_amdgcn_global_load_lds(
        (const __attribute__((address_space(1))) void*)g,
        (__attribute__((address_space(3))) void*)l, 16, 0, 0);
}

// ---------------------------------------------------------------------------
// K0: prep. blocks 0-191: transpose-cast weights -> Wt/Wot bf16, stored with
// per-row 16B-chunk swizzle (chunk^=(row&7) within each 64-elem K-tile) so
// the GEMMs can stage via linear global_load_lds and still read fragments
// bank-spread. blocks 192-703: cast x -> xb bf16, same swizzled layout.
// ---------------------------------------------------------------------------
__global__ __launch_bounds__(256) void prep(const float* __restrict__ x,
    const float* __restrict__ Wq, const float* __restrict__ Wk,
    const float* __restrict__ Wv, const float* __restrict__ Wo,
    u16* __restrict__ xb, u16* __restrict__ Wt, u16* __restrict__ Wot)
{
    const int tid = threadIdx.x, bid = blockIdx.x;
    if (bid >= 192) {   // x cast (one 16B chunk per thread)
        int i = ((bid - 192) * 256 + tid) * 8;
        int row = i >> 9, col = i & 511;
        int scol = (col & ~63) | ((((col >> 3) & 7) ^ (row & 7)) << 3);
        float4 v0 = *(const float4*)(x + i);
        float4 v1 = *(const float4*)(x + i + 4);
        s16x8 o;
        o[0] = (short)f2b(v0.x); o[1] = (short)f2b(v0.y);
        o[2] = (short)f2b(v0.z); o[3] = (short)f2b(v0.w);
        o[4] = (short)f2b(v1.x); o[5] = (short)f2b(v1.y);
        o[6] = (short)f2b(v1.z); o[7] = (short)f2b(v1.w);
        *(s16x8*)(xb + (size_t)row * 512 + scol) = o;
        return;
    }
    __shared__ u16 Tsh[64][72];
    const float* src; u16* dst; int N, base, kt, nt;
    if (bid < 64)       { src = Wq; dst = Wt;  N = 512; base = 0;   kt = bid >> 3;       nt = bid & 7; }
    else if (bid < 96)  { src = Wk; dst = Wt;  N = 256; base = 512; kt = (bid-64) >> 2;  nt = (bid-64) & 3; }
    else if (bid < 128) { src = Wv; dst = Wt;  N = 256; base = 768; kt = (bid-96) >> 2;  nt = (bid-96) & 3; }
    else                { src = Wo; dst = Wot; N = 512; base = 0;   kt = (bid-128) >> 3; nt = (bid-128) & 7; }
    const int k0 = kt * 64, n0 = nt * 64;
    const int r = tid >> 2, c0 = (tid & 3) * 16;
#pragma unroll
    for (int j = 0; j < 4; ++j) {
        float4 v = *(const float4*)(src + (size_t)(k0 + r) * N + n0 + c0 + j * 4);
        Tsh[c0 + j*4 + 0][r] = f2b(v.x);
        Tsh[c0 + j*4 + 1][r] = f2b(v.y);
        Tsh[c0 + j*4 + 2][r] = f2b(v.z);
        Tsh[c0 + j*4 + 3][r] = f2b(v.w);
    }
    __syncthreads();
    const int n = tid >> 2, kc = (tid & 3) * 16;
    const int r7 = n & 7;
    const int cc0 = (kc >> 3) ^ r7;
    const int cc1 = ((kc >> 3) + 1) ^ r7;
    u16* oprow = dst + (size_t)(base + n0 + n) * 512 + k0;
    *(s16x8*)(oprow + cc0 * 8) = *(const s16x8*)&Tsh[n][kc];
    *(s16x8*)(oprow + cc1 * 8) = *(const s16x8*)&Tsh[n][kc + 8];
}

// ---------------------------------------------------------------------------
// bf16 MFMA GEMM with global_load_lds staging. A and Bt must be stored in
// the swizzled layout above. LDS tiles are LINEAR [64][64]; fragment reads
// apply chunk = (g + kk/8) ^ (q&7) -> 8 bank-groups x 2 lanes (free).
// Per K-step per thread: 4 async gload16, 0 ds_writes.
// ---------------------------------------------------------------------------
template<typename OutT>
__global__ __launch_bounds__(256) void gemm_mfma(const u16* __restrict__ A,
    const u16* __restrict__ Bt, OutT* __restrict__ C, int ldc)
{
    __shared__ u16 Ash[64][64];
    __shared__ u16 Bsh[64][64];
    const int tid = threadIdx.x;
    const int m0b = blockIdx.y * 64, n0b = blockIdx.x * 64;
    const int lane = tid & 63, wv = tid >> 6;
    const int q = lane & 15, g = lane >> 4;
    const int wm = (wv & 1) * 32, wn = (wv >> 1) * 32;
    const int lrow = lane >> 3, lchunk = lane & 7;   // staging map
    const int s7 = q & 7;
    f32x4 acc[2][2] = {{{0,0,0,0},{0,0,0,0}},{{0,0,0,0},{0,0,0,0}}};
    for (int k0 = 0; k0 < 512; k0 += 64) {
        __syncthreads();   // previous iteration's fragment reads done
#pragma unroll
        for (int is = 0; is < 2; ++is) {
            const int rbase = is * 32 + wv * 8;
            gload16(A  + (size_t)(m0b + rbase + lrow) * 512 + k0 + lchunk * 8,
                    &Ash[rbase][0]);
            gload16(Bt + (size_t)(n0b + rbase + lrow) * 512 + k0 + lchunk * 8,
                    &Bsh[rbase][0]);
        }
        __syncthreads();   // vmcnt(0) drained by compiler before barrier
#pragma unroll
        for (int kk = 0; kk < 64; kk += 32) {
            const int cs = ((kk >> 3) + g) ^ s7;
            s16x8 af0 = *(const s16x8*)&Ash[wm + q][cs * 8];
            s16x8 af1 = *(const s16x8*)&Ash[wm + 16 + q][cs * 8];
            s16x8 bf0 = *(const s16x8*)&Bsh[wn + q][cs * 8];
            s16x8 bf1 = *(const s16x8*)&Bsh[wn + 16 + q][cs * 8];
            acc[0][0] = __builtin_amdgcn_mfma_f32_16x16x32_bf16(af0, bf0, acc[0][0], 0, 0, 0);
            acc[0][1] = __builtin_amdgcn_mfma_f32_16x16x32_bf16(af0, bf1, acc[0][1], 0, 0, 0);
            acc[1][0] = __builtin_amdgcn_mfma_f32_16x16x32_bf16(af1, bf0, acc[1][0], 0, 0, 0);
            acc[1][1] = __builtin_amdgcn_mfma_f32_16x16x32_bf16(af1, bf1, acc[1][1], 0, 0, 0);
        }
    }
#pragma unroll
    for (int mt = 0; mt < 2; ++mt)
#pragma unroll
        for (int nt = 0; nt < 2; ++nt)
#pragma unroll
            for (int r = 0; r < 4; ++r)
                st_out(&C[(size_t)(m0b + wm + mt*16 + g*4 + r) * ldc + n0b + wn + nt*16 + q],
                       acc[mt][nt][r]);
}

// ---------------------------------------------------------------------------
// K2: GQA-merged sliding-window attention with fused RoPE+RMS (R13 winner).
// Reads qkvb (UNswizzled). Writes attb in the swizzled chunk layout so
// oproj can gload_lds-stage it. Block = (kvh, 32-query tile).
// ---------------------------------------------------------------------------
__global__ __launch_bounds__(256) void swa_mfma(const u16* __restrict__ qkvb,
    const float* __restrict__ cosT, const float* __restrict__ sinT,
    const float* __restrict__ qw, const float* __restrict__ kw,
    u16* __restrict__ attb)
{
    __shared__ u16 Ksh[160][72];
    __shared__ u16 Vt[64][162];
    const int tid = threadIdx.x;
    const int kvh = blockIdx.y;
    const int t0 = blockIdx.x * 32;
    for (int i = 0; i < 5; ++i) {
        int idx = i * 256 + tid;
        int j = idx >> 3, e = idx & 7, d0 = e * 8;
        int kt = t0 - 127 + j;
        if (kt < 0 || kt >= 2048) {
            s16x8 z = {0,0,0,0,0,0,0,0};
            *(s16x8*)&Ksh[j][d0] = z;
        } else {
            s16x8 raw = *(const s16x8*)(qkvb + (size_t)kt * 1024 + 512 + kvh * 64 + d0);
            float kv[8], ov[8];
#pragma unroll
            for (int ii = 0; ii < 8; ++ii) kv[ii] = b2f((u16)raw[ii]);
#pragma unroll
            for (int ii = 0; ii < 8; ++ii) ov[ii] = __shfl_xor(kv[ii], 4);
            const float* cp = cosT + kt * 32 + (e & 3) * 8;
            const float* sp = sinT + kt * 32 + (e & 3) * 8;
            float4 c0 = *(const float4*)(cp), c1 = *(const float4*)(cp + 4);
            float4 s0 = *(const float4*)(sp), s1 = *(const float4*)(sp + 4);
            float cf[8] = {c0.x,c0.y,c0.z,c0.w,c1.x,c1.y,c1.z,c1.w};
            float sf[8] = {s0.x,s0.y,s0.z,s0.w,s1.x,s1.y,s1.z,s1.w};
            const bool lo = (e < 4);
            float r[8]; float ssl = 0.f;
#pragma unroll
            for (int ii = 0; ii < 8; ++ii) {
                r[ii] = lo ? (kv[ii]*cf[ii] - ov[ii]*sf[ii])
                           : (kv[ii]*cf[ii] + ov[ii]*sf[ii]);
                ssl += r[ii] * r[ii];
            }
            ssl += __shfl_xor(ssl, 1);
            ssl += __shfl_xor(ssl, 2);
            ssl += __shfl_xor(ssl, 4);
            float scale = rsqrtf(ssl * (1.0f / 64.0f) + 1e-6f);
            float4 w0 = *(const float4*)(kw + d0), w1 = *(const float4*)(kw + d0 + 4);
            float wf[8] = {w0.x,w0.y,w0.z,w0.w,w1.x,w1.y,w1.z,w1.w};
            s16x8 outv;
#pragma unroll
            for (int ii = 0; ii < 8; ++ii) outv[ii] = (short)f2b(r[ii] * scale * wf[ii]);
            *(s16x8*)&Ksh[j][d0] = outv;
        }
    }
    for (int cch = 0; cch < 5; ++cch) {
        int w  = cch * 32 + (tid & 31);
        int d0 = (tid >> 5) * 8;
        int kt = t0 - 127 + w;
        s16x8 val = {0,0,0,0,0,0,0,0};
        if (kt >= 0 && kt < 2048)
            val = *(const s16x8*)(qkvb + (size_t)kt * 1024 + 768 + kvh * 64 + d0);
#pragma unroll
        for (int jj = 0; jj < 8; ++jj) Vt[d0 + jj][w] = ((const u16*)&val)[jj];
    }
    const int wv = tid >> 6, lane = tid & 63;
    const int q = lane & 15, g = lane >> 4;
    const int h  = 2 * kvh + (wv >> 1);
    const int tw = t0 + (wv & 1) * 16;
    const int jb = (wv & 1) * 16;
    const int t = tw + q;
    s16x8 qf0, qf1;
    {
        const u16* qp = qkvb + (size_t)t * 1024 + h * 64;
        s16x8 q0r = *(const s16x8*)(qp + g * 8);
        s16x8 q1r = *(const s16x8*)(qp + 32 + g * 8);
        const float* cp = cosT + t * 32 + g * 8;
        const float* sp = sinT + t * 32 + g * 8;
        float4 c0 = *(const float4*)(cp), c1 = *(const float4*)(cp + 4);
        float4 s0 = *(const float4*)(sp), s1 = *(const float4*)(sp + 4);
        float cf[8] = {c0.x,c0.y,c0.z,c0.w,c1.x,c1.y,c1.z,c1.w};
        float sf[8] = {s0.x,s0.y,s0.z,s0.w,s1.x,s1.y,s1.z,s1.w};
        float rl[8], rh[8]; float ssl = 0.f;
#pragma unroll
        for (int ii = 0; ii < 8; ++ii) {
            float ql = b2f((u16)q0r[ii]), qh = b2f((u16)q1r[ii]);
            rl[ii] = ql * cf[ii] - qh * sf[ii];
            rh[ii] = qh * cf[ii] + ql * sf[ii];
            ssl += rl[ii]*rl[ii] + rh[ii]*rh[ii];
        }
        ssl += __shfl_xor(ssl, 16);
        ssl += __shfl_xor(ssl, 32);
        float scale = rsqrtf(ssl * (1.0f / 64.0f) + 1e-6f);
        float4 wl0 = *(const float4*)(qw + g * 8), wl1 = *(const float4*)(qw + g * 8 + 4);
        float4 wh0 = *(const float4*)(qw + 32 + g * 8), wh1 = *(const float4*)(qw + 32 + g * 8 + 4);
        float wlo[8] = {wl0.x,wl0.y,wl0.z,wl0.w,wl1.x,wl1.y,wl1.z,wl1.w};
        float whi[8] = {wh0.x,wh0.y,wh0.z,wh0.w,wh1.x,wh1.y,wh1.z,wh1.w};
#pragma unroll
        for (int ii = 0; ii < 8; ++ii) {
            qf0[ii] = (short)f2b(rl[ii] * scale * wlo[ii]);
            qf1[ii] = (short)f2b(rh[ii] * scale * whi[ii]);
        }
    }
    __syncthreads();
    float s[9][4];
    float mx = -INFINITY;
    for (int wt = 0; wt < 9; ++wt) {
        int ldsrow = jb + wt * 16 + q;
        s16x8 kf0 = *(const s16x8*)&Ksh[ldsrow][g * 8];
        s16x8 kf1 = *(const s16x8*)&Ksh[ldsrow][32 + g * 8];
        f32x4 accv = {0, 0, 0, 0};
        accv = __builtin_amdgcn_mfma_f32_16x16x32_bf16(kf0, qf0, accv, 0, 0, 0);
        accv = __builtin_amdgcn_mfma_f32_16x16x32_bf16(kf1, qf1, accv, 0, 0, 0);
#pragma unroll
        for (int r = 0; r < 4; ++r) {
            int woff = wt * 16 + g * 4 + r;
            int key  = tw - 127 + woff;
            bool ok = (woff >= q) && (woff <= q + 127) && (key >= 0);
            float sv = ok ? accv[r] * 0.125f : -INFINITY;
            s[wt][r] = sv;
            mx = fmaxf(mx, sv);
        }
    }
    mx = fmaxf(mx, __shfl_xor(mx, 16));
    mx = fmaxf(mx, __shfl_xor(mx, 32));
    float sum = 0.f;
    s16x4 pb[9];
    for (int wt = 0; wt < 9; ++wt) {
#pragma unroll
        for (int r = 0; r < 4; ++r) {
            float p = __expf(s[wt][r] - mx);
            sum += p;
            pb[wt][r] = (short)f2b(p);
        }
    }
    sum += __shfl_xor(sum, 16);
    sum += __shfl_xor(sum, 32);
    float inv = 1.0f / sum;
    f32x4 oacc[4];
#pragma unroll
    for (int dt = 0; dt < 4; ++dt) {
        f32x4 a = {0, 0, 0, 0};
        for (int wt = 0; wt < 9; ++wt) {
            int col = jb + wt * 16 + g * 4;
            s16x4 vf = *(const s16x4*)&Vt[dt * 16 + q][col];
            a = __builtin_amdgcn_mfma_f32_16x16x16bf16_1k(vf, pb[wt], a, 0, 0, 0);
        }
        oacc[dt] = a;
    }
    __syncthreads();
    float (*Osh)[16][68] = (float (*)[16][68])&Ksh[0][0];
#pragma unroll
    for (int dt = 0; dt < 4; ++dt)
#pragma unroll
        for (int r = 0; r < 4; ++r)
            Osh[wv][q][dt * 16 + g * 4 + r] = oacc[dt][r] * inv;
    __syncthreads();
    // attb write in SWIZZLED chunk layout (row&7 = qq&7 since tw % 16 == 0)
    const int qq = lane >> 2, dd0 = (lane & 3) * 16;
    const int r7 = qq & 7;
    u16* oprow = attb + (size_t)(tw + qq) * 512 + h * 64;
    s16x8 v0, v1;
#pragma unroll
    for (int j = 0; j < 8; ++j) v0[j] = (short)f2b(Osh[wv][qq][dd0 + j]);
#pragma unroll
    for (int j = 0; j < 8; ++j) v1[j] = (short)f2b(Osh[wv][qq][dd0 + 8 + j]);
    const int cc0 = (dd0 >> 3) ^ r7;
    const int cc1 = ((dd0 >> 3) + 1) ^ r7;
    *(s16x8*)(oprow + cc0 * 8) = v0;
    *(s16x8*)(oprow + cc1 * 8) = v1;
}

// ---------------------------------------------------------------------------
// Workspace: xb [2048*512 u16] | Wt [1024*512] | Wot [512*512] |
//            qkvb [2048*1024] | attb [2048*512]  ≈ 9.5 MB
// ---------------------------------------------------------------------------
extern "C" void kernel_launch(void* const* d_in, const int* in_sizes, int n_in,
                              void* d_out, int out_size, void* d_ws, size_t ws_size,
                              hipStream_t stream)
{
    const float* x    = (const float*)d_in[0];
    const float* Wq   = (const float*)d_in[1];
    const float* Wk   = (const float*)d_in[2];
    const float* Wv   = (const float*)d_in[3];
    const float* Wo   = (const float*)d_in[4];
    const float* qw   = (const float*)d_in[5];
    const float* kw   = (const float*)d_in[6];
    const float* cosT = (const float*)d_in[7];
    const float* sinT = (const float*)d_in[8];

    u16* ws   = (u16*)d_ws;
    u16* xb   = ws;                               // 2048*512
    u16* Wt   = xb   + (size_t)2048 * 512;        // 1024*512
    u16* Wot  = Wt   + (size_t)1024 * 512;        // 512*512
    u16* qkvb = Wot  + (size_t)512 * 512;         // 2048*1024
    u16* attb = qkvb + (size_t)2048 * 1024;       // 2048*512

    dim3 blk(256);
    hipLaunchKernelGGL(prep, dim3(704), blk, 0, stream, x, Wq, Wk, Wv, Wo, xb, Wt, Wot);
    hipLaunchKernelGGL((gemm_mfma<u16>), dim3(16, 32), blk, 0, stream, xb, Wt, qkvb, 1024);
    hipLaunchKernelGGL(swa_mfma, dim3(64, 4), blk, 0, stream,
                       qkvb, cosT, sinT, qw, kw, attb);
    hipLaunchKernelGGL((gemm_mfma<float>), dim3(8, 32), blk, 0, stream,
                       attb, Wot, (float*)d_out, 512);
}

// Round 15
// 33.728 us; speedup vs baseline: 1.0913x; 1.0138x over previous
//
#include <hip/hip_runtime.h>
#include <hip/hip_bf16.h>
#include <math.h>

typedef float  f32x4  __attribute__((ext_vector_type(4)));
typedef short  s16x4  __attribute__((ext_vector_type(4)));
typedef short  s16x8  __attribute__((ext_vector_type(8)));
typedef unsigned short u16;

__device__ inline u16 f2b(float f) {
    __hip_bfloat16 h = __float2bfloat16(f);
    return *reinterpret_cast<u16*>(&h);
}
__device__ inline float b2f(u16 v) {
    return __uint_as_float(((unsigned)v) << 16);
}
__device__ inline void st_out(float* p, float v) { *p = v; }
__device__ inline void st_out(u16* p, float v)   { *p = f2b(v); }

// async global->LDS, 16B per lane; LDS dest = uniform base + lane*16.
__device__ inline void gload16(const void* g, void* l) {
    __builtin_amdgcn_global_load_lds(
        (const __attribute__((address_space(1))) void*)g,
        (__attribute__((address_space(3))) void*)l, 16, 0, 0);
}

// ---------------------------------------------------------------------------
// K0: prep. blocks 0-191: transpose-cast weights -> Wt/Wot bf16, stored with
// per-row 16B-chunk swizzle (chunk^=(row&7) within each 64-elem K-tile).
// blocks 192-703: cast x -> xb bf16, same swizzled layout.
// ---------------------------------------------------------------------------
__global__ __launch_bounds__(256) void prep(const float* __restrict__ x,
    const float* __restrict__ Wq, const float* __restrict__ Wk,
    const float* __restrict__ Wv, const float* __restrict__ Wo,
    u16* __restrict__ xb, u16* __restrict__ Wt, u16* __restrict__ Wot)
{
    const int tid = threadIdx.x, bid = blockIdx.x;
    if (bid >= 192) {   // x cast (one 16B chunk per thread)
        int i = ((bid - 192) * 256 + tid) * 8;
        int row = i >> 9, col = i & 511;
        int scol = (col & ~63) | ((((col >> 3) & 7) ^ (row & 7)) << 3);
        float4 v0 = *(const float4*)(x + i);
        float4 v1 = *(const float4*)(x + i + 4);
        s16x8 o;
        o[0] = (short)f2b(v0.x); o[1] = (short)f2b(v0.y);
        o[2] = (short)f2b(v0.z); o[3] = (short)f2b(v0.w);
        o[4] = (short)f2b(v1.x); o[5] = (short)f2b(v1.y);
        o[6] = (short)f2b(v1.z); o[7] = (short)f2b(v1.w);
        *(s16x8*)(xb + (size_t)row * 512 + scol) = o;
        return;
    }
    __shared__ u16 Tsh[64][72];
    const float* src; u16* dst; int N, base, kt, nt;
    if (bid < 64)       { src = Wq; dst = Wt;  N = 512; base = 0;   kt = bid >> 3;       nt = bid & 7; }
    else if (bid < 96)  { src = Wk; dst = Wt;  N = 256; base = 512; kt = (bid-64) >> 2;  nt = (bid-64) & 3; }
    else if (bid < 128) { src = Wv; dst = Wt;  N = 256; base = 768; kt = (bid-96) >> 2;  nt = (bid-96) & 3; }
    else                { src = Wo; dst = Wot; N = 512; base = 0;   kt = (bid-128) >> 3; nt = (bid-128) & 7; }
    const int k0 = kt * 64, n0 = nt * 64;
    const int r = tid >> 2, c0 = (tid & 3) * 16;
#pragma unroll
    for (int j = 0; j < 4; ++j) {
        float4 v = *(const float4*)(src + (size_t)(k0 + r) * N + n0 + c0 + j * 4);
        Tsh[c0 + j*4 + 0][r] = f2b(v.x);
        Tsh[c0 + j*4 + 1][r] = f2b(v.y);
        Tsh[c0 + j*4 + 2][r] = f2b(v.z);
        Tsh[c0 + j*4 + 3][r] = f2b(v.w);
    }
    __syncthreads();
    const int n = tid >> 2, kc = (tid & 3) * 16;
    const int r7 = n & 7;
    const int cc0 = (kc >> 3) ^ r7;
    const int cc1 = ((kc >> 3) + 1) ^ r7;
    u16* oprow = dst + (size_t)(base + n0 + n) * 512 + k0;
    *(s16x8*)(oprow + cc0 * 8) = *(const s16x8*)&Tsh[n][kc];
    *(s16x8*)(oprow + cc1 * 8) = *(const s16x8*)&Tsh[n][kc + 8];
}

// ---------------------------------------------------------------------------
// bf16 MFMA GEMM, gload_lds staging + counted-vmcnt double-buffer pipeline.
// Per iteration: issue tile it+1's 4 async loads -> wait vmcnt(4) (tile it's
// loads, issued one iteration ago, latency hidden under prior MFMA) -> raw
// barrier (no drain) -> MFMA buf[it&1] -> raw barrier (protects buf reuse).
// A/Bt in swizzled chunk layout; fragment chunk = (g + kk/8) ^ (q&7).
// ---------------------------------------------------------------------------
template<typename OutT>
__global__ __launch_bounds__(256) void gemm_mfma(const u16* __restrict__ A,
    const u16* __restrict__ Bt, OutT* __restrict__ C, int ldc)
{
    __shared__ u16 Ash[2][64][64];
    __shared__ u16 Bsh[2][64][64];
    const int tid = threadIdx.x;
    const int m0b = blockIdx.y * 64, n0b = blockIdx.x * 64;
    const int lane = tid & 63, wv = tid >> 6;
    const int q = lane & 15, g = lane >> 4;
    const int wm = (wv & 1) * 32, wn = (wv >> 1) * 32;
    const int lrow = lane >> 3, lchunk = lane & 7;   // staging map
    const int s7 = q & 7;
    const int r0 = wv * 8, r1 = 32 + wv * 8;         // this wave's staging rows
    f32x4 acc[2][2] = {{{0,0,0,0},{0,0,0,0}},{{0,0,0,0},{0,0,0,0}}};

    // prologue: issue tile 0 into buf 0
    {
        gload16(A  + (size_t)(m0b + r0 + lrow) * 512 + lchunk * 8, &Ash[0][r0][0]);
        gload16(Bt + (size_t)(n0b + r0 + lrow) * 512 + lchunk * 8, &Bsh[0][r0][0]);
        gload16(A  + (size_t)(m0b + r1 + lrow) * 512 + lchunk * 8, &Ash[0][r1][0]);
        gload16(Bt + (size_t)(n0b + r1 + lrow) * 512 + lchunk * 8, &Bsh[0][r1][0]);
    }
#pragma unroll
    for (int it = 0; it < 8; ++it) {
        const int cur = it & 1, nxt = cur ^ 1;
        if (it < 7) {   // issue next tile's loads (latency hidden under MFMA)
            const int k0 = (it + 1) * 64;
            gload16(A  + (size_t)(m0b + r0 + lrow) * 512 + k0 + lchunk * 8, &Ash[nxt][r0][0]);
            gload16(Bt + (size_t)(n0b + r0 + lrow) * 512 + k0 + lchunk * 8, &Bsh[nxt][r0][0]);
            gload16(A  + (size_t)(m0b + r1 + lrow) * 512 + k0 + lchunk * 8, &Ash[nxt][r1][0]);
            gload16(Bt + (size_t)(n0b + r1 + lrow) * 512 + k0 + lchunk * 8, &Bsh[nxt][r1][0]);
            asm volatile("s_waitcnt vmcnt(4)" ::: "memory");   // tile it landed
        } else {
            asm volatile("s_waitcnt vmcnt(0)" ::: "memory");   // last tile landed
        }
        __builtin_amdgcn_sched_barrier(0);
        __builtin_amdgcn_s_barrier();        // all waves' tile-it loads visible
        __builtin_amdgcn_sched_barrier(0);
#pragma unroll
        for (int kk = 0; kk < 64; kk += 32) {
            const int cs = ((kk >> 3) + g) ^ s7;
            s16x8 af0 = *(const s16x8*)&Ash[cur][wm + q][cs * 8];
            s16x8 af1 = *(const s16x8*)&Ash[cur][wm + 16 + q][cs * 8];
            s16x8 bf0 = *(const s16x8*)&Bsh[cur][wn + q][cs * 8];
            s16x8 bf1 = *(const s16x8*)&Bsh[cur][wn + 16 + q][cs * 8];
            acc[0][0] = __builtin_amdgcn_mfma_f32_16x16x32_bf16(af0, bf0, acc[0][0], 0, 0, 0);
            acc[0][1] = __builtin_amdgcn_mfma_f32_16x16x32_bf16(af0, bf1, acc[0][1], 0, 0, 0);
            acc[1][0] = __builtin_amdgcn_mfma_f32_16x16x32_bf16(af1, bf0, acc[1][0], 0, 0, 0);
            acc[1][1] = __builtin_amdgcn_mfma_f32_16x16x32_bf16(af1, bf1, acc[1][1], 0, 0, 0);
        }
        __builtin_amdgcn_sched_barrier(0);
        __builtin_amdgcn_s_barrier();        // reads of buf[cur] done before reuse
        __builtin_amdgcn_sched_barrier(0);
    }
#pragma unroll
    for (int mt = 0; mt < 2; ++mt)
#pragma unroll
        for (int nt = 0; nt < 2; ++nt)
#pragma unroll
            for (int r = 0; r < 4; ++r)
                st_out(&C[(size_t)(m0b + wm + mt*16 + g*4 + r) * ldc + n0b + wn + nt*16 + q],
                       acc[mt][nt][r]);
}

// ---------------------------------------------------------------------------
// K2: GQA-merged sliding-window attention with fused RoPE+RMS (R13 winner).
// Reads qkvb (UNswizzled). Writes attb in the swizzled chunk layout.
// ---------------------------------------------------------------------------
__global__ __launch_bounds__(256) void swa_mfma(const u16* __restrict__ qkvb,
    const float* __restrict__ cosT, const float* __restrict__ sinT,
    const float* __restrict__ qw, const float* __restrict__ kw,
    u16* __restrict__ attb)
{
    __shared__ u16 Ksh[160][72];
    __shared__ u16 Vt[64][162];
    const int tid = threadIdx.x;
    const int kvh = blockIdx.y;
    const int t0 = blockIdx.x * 32;
    for (int i = 0; i < 5; ++i) {
        int idx = i * 256 + tid;
        int j = idx >> 3, e = idx & 7, d0 = e * 8;
        int kt = t0 - 127 + j;
        if (kt < 0 || kt >= 2048) {
            s16x8 z = {0,0,0,0,0,0,0,0};
            *(s16x8*)&Ksh[j][d0] = z;
        } else {
            s16x8 raw = *(const s16x8*)(qkvb + (size_t)kt * 1024 + 512 + kvh * 64 + d0);
            float kv[8], ov[8];
#pragma unroll
            for (int ii = 0; ii < 8; ++ii) kv[ii] = b2f((u16)raw[ii]);
#pragma unroll
            for (int ii = 0; ii < 8; ++ii) ov[ii] = __shfl_xor(kv[ii], 4);
            const float* cp = cosT + kt * 32 + (e & 3) * 8;
            const float* sp = sinT + kt * 32 + (e & 3) * 8;
            float4 c0 = *(const float4*)(cp), c1 = *(const float4*)(cp + 4);
            float4 s0 = *(const float4*)(sp), s1 = *(const float4*)(sp + 4);
            float cf[8] = {c0.x,c0.y,c0.z,c0.w,c1.x,c1.y,c1.z,c1.w};
            float sf[8] = {s0.x,s0.y,s0.z,s0.w,s1.x,s1.y,s1.z,s1.w};
            const bool lo = (e < 4);
            float r[8]; float ssl = 0.f;
#pragma unroll
            for (int ii = 0; ii < 8; ++ii) {
                r[ii] = lo ? (kv[ii]*cf[ii] - ov[ii]*sf[ii])
                           : (kv[ii]*cf[ii] + ov[ii]*sf[ii]);
                ssl += r[ii] * r[ii];
            }
            ssl += __shfl_xor(ssl, 1);
            ssl += __shfl_xor(ssl, 2);
            ssl += __shfl_xor(ssl, 4);
            float scale = rsqrtf(ssl * (1.0f / 64.0f) + 1e-6f);
            float4 w0 = *(const float4*)(kw + d0), w1 = *(const float4*)(kw + d0 + 4);
            float wf[8] = {w0.x,w0.y,w0.z,w0.w,w1.x,w1.y,w1.z,w1.w};
            s16x8 outv;
#pragma unroll
            for (int ii = 0; ii < 8; ++ii) outv[ii] = (short)f2b(r[ii] * scale * wf[ii]);
            *(s16x8*)&Ksh[j][d0] = outv;
        }
    }
    for (int cch = 0; cch < 5; ++cch) {
        int w  = cch * 32 + (tid & 31);
        int d0 = (tid >> 5) * 8;
        int kt = t0 - 127 + w;
        s16x8 val = {0,0,0,0,0,0,0,0};
        if (kt >= 0 && kt < 2048)
            val = *(const s16x8*)(qkvb + (size_t)kt * 1024 + 768 + kvh * 64 + d0);
#pragma unroll
        for (int jj = 0; jj < 8; ++jj) Vt[d0 + jj][w] = ((const u16*)&val)[jj];
    }
    const int wv = tid >> 6, lane = tid & 63;
    const int q = lane & 15, g = lane >> 4;
    const int h  = 2 * kvh + (wv >> 1);
    const int tw = t0 + (wv & 1) * 16;
    const int jb = (wv & 1) * 16;
    const int t = tw + q;
    s16x8 qf0, qf1;
    {
        const u16* qp = qkvb + (size_t)t * 1024 + h * 64;
        s16x8 q0r = *(const s16x8*)(qp + g * 8);
        s16x8 q1r = *(const s16x8*)(qp + 32 + g * 8);
        const float* cp = cosT + t * 32 + g * 8;
        const float* sp = sinT + t * 32 + g * 8;
        float4 c0 = *(const float4*)(cp), c1 = *(const float4*)(cp + 4);
        float4 s0 = *(const float4*)(sp), s1 = *(const float4*)(sp + 4);
        float cf[8] = {c0.x,c0.y,c0.z,c0.w,c1.x,c1.y,c1.z,c1.w};
        float sf[8] = {s0.x,s0.y,s0.z,s0.w,s1.x,s1.y,s1.z,s1.w};
        float rl[8], rh[8]; float ssl = 0.f;
#pragma unroll
        for (int ii = 0; ii < 8; ++ii) {
            float ql = b2f((u16)q0r[ii]), qh = b2f((u16)q1r[ii]);
            rl[ii] = ql * cf[ii] - qh * sf[ii];
            rh[ii] = qh * cf[ii] + ql * sf[ii];
            ssl += rl[ii]*rl[ii] + rh[ii]*rh[ii];
        }
        ssl += __shfl_xor(ssl, 16);
        ssl += __shfl_xor(ssl, 32);
        float scale = rsqrtf(ssl * (1.0f / 64.0f) + 1e-6f);
        float4 wl0 = *(const float4*)(qw + g * 8), wl1 = *(const float4*)(qw + g * 8 + 4);
        float4 wh0 = *(const float4*)(qw + 32 + g * 8), wh1 = *(const float4*)(qw + 32 + g * 8 + 4);
        float wlo[8] = {wl0.x,wl0.y,wl0.z,wl0.w,wl1.x,wl1.y,wl1.z,wl1.w};
        float whi[8] = {wh0.x,wh0.y,wh0.z,wh0.w,wh1.x,wh1.y,wh1.z,wh1.w};
#pragma unroll
        for (int ii = 0; ii < 8; ++ii) {
            qf0[ii] = (short)f2b(rl[ii] * scale * wlo[ii]);
            qf1[ii] = (short)f2b(rh[ii] * scale * whi[ii]);
        }
    }
    __syncthreads();
    float s[9][4];
    float mx = -INFINITY;
    for (int wt = 0; wt < 9; ++wt) {
        int ldsrow = jb + wt * 16 + q;
        s16x8 kf0 = *(const s16x8*)&Ksh[ldsrow][g * 8];
        s16x8 kf1 = *(const s16x8*)&Ksh[ldsrow][32 + g * 8];
        f32x4 accv = {0, 0, 0, 0};
        accv = __builtin_amdgcn_mfma_f32_16x16x32_bf16(kf0, qf0, accv, 0, 0, 0);
        accv = __builtin_amdgcn_mfma_f32_16x16x32_bf16(kf1, qf1, accv, 0, 0, 0);
#pragma unroll
        for (int r = 0; r < 4; ++r) {
            int woff = wt * 16 + g * 4 + r;
            int key  = tw - 127 + woff;
            bool ok = (woff >= q) && (woff <= q + 127) && (key >= 0);
            float sv = ok ? accv[r] * 0.125f : -INFINITY;
            s[wt][r] = sv;
            mx = fmaxf(mx, sv);
        }
    }
    mx = fmaxf(mx, __shfl_xor(mx, 16));
    mx = fmaxf(mx, __shfl_xor(mx, 32));
    float sum = 0.f;
    s16x4 pb[9];
    for (int wt = 0; wt < 9; ++wt) {
#pragma unroll
        for (int r = 0; r < 4; ++r) {
            float p = __expf(s[wt][r] - mx);
            sum += p;
            pb[wt][r] = (short)f2b(p);
        }
    }
    sum += __shfl_xor(sum, 16);
    sum += __shfl_xor(sum, 32);
    float inv = 1.0f / sum;
    f32x4 oacc[4];
#pragma unroll
    for (int dt = 0; dt < 4; ++dt) {
        f32x4 a = {0, 0, 0, 0};
        for (int wt = 0; wt < 9; ++wt) {
            int col = jb + wt * 16 + g * 4;
            s16x4 vf = *(const s16x4*)&Vt[dt * 16 + q][col];
            a = __builtin_amdgcn_mfma_f32_16x16x16bf16_1k(vf, pb[wt], a, 0, 0, 0);
        }
        oacc[dt] = a;
    }
    __syncthreads();
    float (*Osh)[16][68] = (float (*)[16][68])&Ksh[0][0];
#pragma unroll
    for (int dt = 0; dt < 4; ++dt)
#pragma unroll
        for (int r = 0; r < 4; ++r)
            Osh[wv][q][dt * 16 + g * 4 + r] = oacc[dt][r] * inv;
    __syncthreads();
    const int qq = lane >> 2, dd0 = (lane & 3) * 16;
    const int r7 = qq & 7;
    u16* oprow = attb + (size_t)(tw + qq) * 512 + h * 64;
    s16x8 v0, v1;
#pragma unroll
    for (int j = 0; j < 8; ++j) v0[j] = (short)f2b(Osh[wv][qq][dd0 + j]);
#pragma unroll
    for (int j = 0; j < 8; ++j) v1[j] = (short)f2b(Osh[wv][qq][dd0 + 8 + j]);
    const int cc0 = (dd0 >> 3) ^ r7;
    const int cc1 = ((dd0 >> 3) + 1) ^ r7;
    *(s16x8*)(oprow + cc0 * 8) = v0;
    *(s16x8*)(oprow + cc1 * 8) = v1;
}

// ---------------------------------------------------------------------------
// Workspace: xb [2048*512 u16] | Wt [1024*512] | Wot [512*512] |
//            qkvb [2048*1024] | attb [2048*512]  ≈ 9.5 MB
// ---------------------------------------------------------------------------
extern "C" void kernel_launch(void* const* d_in, const int* in_sizes, int n_in,
                              void* d_out, int out_size, void* d_ws, size_t ws_size,
                              hipStream_t stream)
{
    const float* x    = (const float*)d_in[0];
    const float* Wq   = (const float*)d_in[1];
    const float* Wk   = (const float*)d_in[2];
    const float* Wv   = (const float*)d_in[3];
    const float* Wo   = (const float*)d_in[4];
    const float* qw   = (const float*)d_in[5];
    const float* kw   = (const float*)d_in[6];
    const float* cosT = (const float*)d_in[7];
    const float* sinT = (const float*)d_in[8];

    u16* ws   = (u16*)d_ws;
    u16* xb   = ws;                               // 2048*512
    u16* Wt   = xb   + (size_t)2048 * 512;        // 1024*512
    u16* Wot  = Wt   + (size_t)1024 * 512;        // 512*512
    u16* qkvb = Wot  + (size_t)512 * 512;         // 2048*1024
    u16* attb = qkvb + (size_t)2048 * 1024;       // 2048*512

    dim3 blk(256);
    hipLaunchKernelGGL(prep, dim3(704), blk, 0, stream, x, Wq, Wk, Wv, Wo, xb, Wt, Wot);
    hipLaunchKernelGGL((gemm_mfma<u16>), dim3(16, 32), blk, 0, stream, xb, Wt, qkvb, 1024);
    hipLaunchKernelGGL(swa_mfma, dim3(64, 4), blk, 0, stream,
                       qkvb, cosT, sinT, qw, kw, attb);
    hipLaunchKernelGGL((gemm_mfma<float>), dim3(8, 32), blk, 0, stream,
                       attb, Wot, (float*)d_out, 512);
}

// Round 16
// 32.150 us; speedup vs baseline: 1.1449x; 1.0491x over previous
//
#include <hip/hip_runtime.h>
#include <hip/hip_bf16.h>
#include <math.h>

typedef float  f32x4  __attribute__((ext_vector_type(4)));
typedef short  s16x4  __attribute__((ext_vector_type(4)));
typedef short  s16x8  __attribute__((ext_vector_type(8)));
typedef unsigned short u16;

__device__ inline u16 f2b(float f) {
    __hip_bfloat16 h = __float2bfloat16(f);
    return *reinterpret_cast<u16*>(&h);
}
__device__ inline float b2f(u16 v) {
    return __uint_as_float(((unsigned)v) << 16);
}
__device__ inline void st_out(float* p, float v) { *p = v; }
__device__ inline void st_out(u16* p, float v)   { *p = f2b(v); }

// async global->LDS, 16B per lane; LDS dest = uniform base + lane*16.
__device__ inline void gload16(const void* g, void* l) {
    __builtin_amdgcn_global_load_lds(
        (const __attribute__((address_space(1))) void*)g,
        (__attribute__((address_space(3))) void*)l, 16, 0, 0);
}

// ---------------------------------------------------------------------------
// K0: prep. blocks 0-191: transpose-cast weights -> Wt/Wot bf16, stored with
// per-row 16B-chunk swizzle (chunk^=(row&7) within each 64-elem K-tile).
// blocks 192-703: cast x -> xb bf16, same swizzled layout.
// ---------------------------------------------------------------------------
__global__ __launch_bounds__(256) void prep(const float* __restrict__ x,
    const float* __restrict__ Wq, const float* __restrict__ Wk,
    const float* __restrict__ Wv, const float* __restrict__ Wo,
    u16* __restrict__ xb, u16* __restrict__ Wt, u16* __restrict__ Wot)
{
    const int tid = threadIdx.x, bid = blockIdx.x;
    if (bid >= 192) {   // x cast (one 16B chunk per thread)
        int i = ((bid - 192) * 256 + tid) * 8;
        int row = i >> 9, col = i & 511;
        int scol = (col & ~63) | ((((col >> 3) & 7) ^ (row & 7)) << 3);
        float4 v0 = *(const float4*)(x + i);
        float4 v1 = *(const float4*)(x + i + 4);
        s16x8 o;
        o[0] = (short)f2b(v0.x); o[1] = (short)f2b(v0.y);
        o[2] = (short)f2b(v0.z); o[3] = (short)f2b(v0.w);
        o[4] = (short)f2b(v1.x); o[5] = (short)f2b(v1.y);
        o[6] = (short)f2b(v1.z); o[7] = (short)f2b(v1.w);
        *(s16x8*)(xb + (size_t)row * 512 + scol) = o;
        return;
    }
    __shared__ u16 Tsh[64][72];
    const float* src; u16* dst; int N, base, kt, nt;
    if (bid < 64)       { src = Wq; dst = Wt;  N = 512; base = 0;   kt = bid >> 3;       nt = bid & 7; }
    else if (bid < 96)  { src = Wk; dst = Wt;  N = 256; base = 512; kt = (bid-64) >> 2;  nt = (bid-64) & 3; }
    else if (bid < 128) { src = Wv; dst = Wt;  N = 256; base = 768; kt = (bid-96) >> 2;  nt = (bid-96) & 3; }
    else                { src = Wo; dst = Wot; N = 512; base = 0;   kt = (bid-128) >> 3; nt = (bid-128) & 7; }
    const int k0 = kt * 64, n0 = nt * 64;
    const int r = tid >> 2, c0 = (tid & 3) * 16;
#pragma unroll
    for (int j = 0; j < 4; ++j) {
        float4 v = *(const float4*)(src + (size_t)(k0 + r) * N + n0 + c0 + j * 4);
        Tsh[c0 + j*4 + 0][r] = f2b(v.x);
        Tsh[c0 + j*4 + 1][r] = f2b(v.y);
        Tsh[c0 + j*4 + 2][r] = f2b(v.z);
        Tsh[c0 + j*4 + 3][r] = f2b(v.w);
    }
    __syncthreads();
    const int n = tid >> 2, kc = (tid & 3) * 16;
    const int r7 = n & 7;
    const int cc0 = (kc >> 3) ^ r7;
    const int cc1 = ((kc >> 3) + 1) ^ r7;
    u16* oprow = dst + (size_t)(base + n0 + n) * 512 + k0;
    *(s16x8*)(oprow + cc0 * 8) = *(const s16x8*)&Tsh[n][kc];
    *(s16x8*)(oprow + cc1 * 8) = *(const s16x8*)&Tsh[n][kc + 8];
}

// ---------------------------------------------------------------------------
// bf16 MFMA GEMM, gload_lds staging + counted-vmcnt double-buffer pipeline
// (verified R15). A/Bt in swizzled chunk layout; fragment chunk =
// (g + kk/8) ^ (q&7).
// ---------------------------------------------------------------------------
template<typename OutT>
__global__ __launch_bounds__(256) void gemm_mfma(const u16* __restrict__ A,
    const u16* __restrict__ Bt, OutT* __restrict__ C, int ldc)
{
    __shared__ u16 Ash[2][64][64];
    __shared__ u16 Bsh[2][64][64];
    const int tid = threadIdx.x;
    const int m0b = blockIdx.y * 64, n0b = blockIdx.x * 64;
    const int lane = tid & 63, wv = tid >> 6;
    const int q = lane & 15, g = lane >> 4;
    const int wm = (wv & 1) * 32, wn = (wv >> 1) * 32;
    const int lrow = lane >> 3, lchunk = lane & 7;   // staging map
    const int s7 = q & 7;
    const int r0 = wv * 8, r1 = 32 + wv * 8;         // this wave's staging rows
    f32x4 acc[2][2] = {{{0,0,0,0},{0,0,0,0}},{{0,0,0,0},{0,0,0,0}}};

    // prologue: issue tile 0 into buf 0
    {
        gload16(A  + (size_t)(m0b + r0 + lrow) * 512 + lchunk * 8, &Ash[0][r0][0]);
        gload16(Bt + (size_t)(n0b + r0 + lrow) * 512 + lchunk * 8, &Bsh[0][r0][0]);
        gload16(A  + (size_t)(m0b + r1 + lrow) * 512 + lchunk * 8, &Ash[0][r1][0]);
        gload16(Bt + (size_t)(n0b + r1 + lrow) * 512 + lchunk * 8, &Bsh[0][r1][0]);
    }
#pragma unroll
    for (int it = 0; it < 8; ++it) {
        const int cur = it & 1, nxt = cur ^ 1;
        if (it < 7) {   // issue next tile's loads (latency hidden under MFMA)
            const int k0 = (it + 1) * 64;
            gload16(A  + (size_t)(m0b + r0 + lrow) * 512 + k0 + lchunk * 8, &Ash[nxt][r0][0]);
            gload16(Bt + (size_t)(n0b + r0 + lrow) * 512 + k0 + lchunk * 8, &Bsh[nxt][r0][0]);
            gload16(A  + (size_t)(m0b + r1 + lrow) * 512 + k0 + lchunk * 8, &Ash[nxt][r1][0]);
            gload16(Bt + (size_t)(n0b + r1 + lrow) * 512 + k0 + lchunk * 8, &Bsh[nxt][r1][0]);
            asm volatile("s_waitcnt vmcnt(4)" ::: "memory");   // tile it landed
        } else {
            asm volatile("s_waitcnt vmcnt(0)" ::: "memory");   // last tile landed
        }
        __builtin_amdgcn_sched_barrier(0);
        __builtin_amdgcn_s_barrier();        // all waves' tile-it loads visible
        __builtin_amdgcn_sched_barrier(0);
#pragma unroll
        for (int kk = 0; kk < 64; kk += 32) {
            const int cs = ((kk >> 3) + g) ^ s7;
            s16x8 af0 = *(const s16x8*)&Ash[cur][wm + q][cs * 8];
            s16x8 af1 = *(const s16x8*)&Ash[cur][wm + 16 + q][cs * 8];
            s16x8 bf0 = *(const s16x8*)&Bsh[cur][wn + q][cs * 8];
            s16x8 bf1 = *(const s16x8*)&Bsh[cur][wn + 16 + q][cs * 8];
            acc[0][0] = __builtin_amdgcn_mfma_f32_16x16x32_bf16(af0, bf0, acc[0][0], 0, 0, 0);
            acc[0][1] = __builtin_amdgcn_mfma_f32_16x16x32_bf16(af0, bf1, acc[0][1], 0, 0, 0);
            acc[1][0] = __builtin_amdgcn_mfma_f32_16x16x32_bf16(af1, bf0, acc[1][0], 0, 0, 0);
            acc[1][1] = __builtin_amdgcn_mfma_f32_16x16x32_bf16(af1, bf1, acc[1][1], 0, 0, 0);
        }
        __builtin_amdgcn_sched_barrier(0);
        __builtin_amdgcn_s_barrier();        // reads of buf[cur] done before reuse
        __builtin_amdgcn_sched_barrier(0);
    }
#pragma unroll
    for (int mt = 0; mt < 2; ++mt)
#pragma unroll
        for (int nt = 0; nt < 2; ++nt)
#pragma unroll
            for (int r = 0; r < 4; ++r)
                st_out(&C[(size_t)(m0b + wm + mt*16 + g*4 + r) * ldc + n0b + wn + nt*16 + q],
                       acc[mt][nt][r]);
}

// ---------------------------------------------------------------------------
// K2: GQA-merged sliding-window attention with fused RoPE+RMS.
// ASYNC-STAGE SPLIT: all 12 global loads (5 K-chunks, 5 V-chunks, 2 Q)
// hoisted to registers up-front (one latency exposure at 1 wave/SIMD),
// then rope/RMS/scatter processing runs on landed registers.
// Reads qkvb (UNswizzled). Writes attb in the swizzled chunk layout.
// ---------------------------------------------------------------------------
__global__ __launch_bounds__(256) void swa_mfma(const u16* __restrict__ qkvb,
    const float* __restrict__ cosT, const float* __restrict__ sinT,
    const float* __restrict__ qw, const float* __restrict__ kw,
    u16* __restrict__ attb)
{
    __shared__ u16 Ksh[160][72];
    __shared__ u16 Vt[64][162];
    const int tid = threadIdx.x;
    const int kvh = blockIdx.y;
    const int t0 = blockIdx.x * 32;
    const int wv = tid >> 6, lane = tid & 63;
    const int q = lane & 15, g = lane >> 4;
    const int h  = 2 * kvh + (wv >> 1);
    const int tw = t0 + (wv & 1) * 16;
    const int jb = (wv & 1) * 16;
    const int t = tw + q;

    // ---- issue ALL global loads up-front (12 in flight per thread) ----
    const s16x8 zz = {0,0,0,0,0,0,0,0};
    s16x8 kraw[5], vraw[5];
#pragma unroll
    for (int i = 0; i < 5; ++i) {
        int idx = i * 256 + tid;
        int j = idx >> 3, d0 = (idx & 7) * 8;
        int kt = t0 - 127 + j;
        kraw[i] = (kt >= 0 && kt < 2048)
            ? *(const s16x8*)(qkvb + (size_t)kt * 1024 + 512 + kvh * 64 + d0) : zz;
    }
#pragma unroll
    for (int cch = 0; cch < 5; ++cch) {
        int w  = cch * 32 + (tid & 31);
        int d0 = (tid >> 5) * 8;
        int kt = t0 - 127 + w;
        vraw[cch] = (kt >= 0 && kt < 2048)
            ? *(const s16x8*)(qkvb + (size_t)kt * 1024 + 768 + kvh * 64 + d0) : zz;
    }
    const u16* qp = qkvb + (size_t)t * 1024 + h * 64;
    s16x8 q0r = *(const s16x8*)(qp + g * 8);
    s16x8 q1r = *(const s16x8*)(qp + 32 + g * 8);

    // ---- K rope + rms -> Ksh (zero rows flow through: rope(0)=0) ----
#pragma unroll
    for (int i = 0; i < 5; ++i) {
        int idx = i * 256 + tid;
        int j = idx >> 3, e = idx & 7, d0 = e * 8;
        int kt = t0 - 127 + j;
        int ktc = (kt < 0) ? 0 : kt;              // clamped for table reads
        float kv[8], ov[8];
#pragma unroll
        for (int ii = 0; ii < 8; ++ii) kv[ii] = b2f((u16)kraw[i][ii]);
#pragma unroll
        for (int ii = 0; ii < 8; ++ii) ov[ii] = __shfl_xor(kv[ii], 4);
        const float* cp = cosT + ktc * 32 + (e & 3) * 8;
        const float* sp = sinT + ktc * 32 + (e & 3) * 8;
        float4 c0 = *(const float4*)(cp), c1 = *(const float4*)(cp + 4);
        float4 s0 = *(const float4*)(sp), s1 = *(const float4*)(sp + 4);
        float cf[8] = {c0.x,c0.y,c0.z,c0.w,c1.x,c1.y,c1.z,c1.w};
        float sf[8] = {s0.x,s0.y,s0.z,s0.w,s1.x,s1.y,s1.z,s1.w};
        const bool lo = (e < 4);
        float r[8]; float ssl = 0.f;
#pragma unroll
        for (int ii = 0; ii < 8; ++ii) {
            r[ii] = lo ? (kv[ii]*cf[ii] - ov[ii]*sf[ii])
                       : (kv[ii]*cf[ii] + ov[ii]*sf[ii]);
            ssl += r[ii] * r[ii];
        }
        ssl += __shfl_xor(ssl, 1);
        ssl += __shfl_xor(ssl, 2);
        ssl += __shfl_xor(ssl, 4);
        float scale = rsqrtf(ssl * (1.0f / 64.0f) + 1e-6f);
        float4 w0 = *(const float4*)(kw + d0), w1 = *(const float4*)(kw + d0 + 4);
        float wf[8] = {w0.x,w0.y,w0.z,w0.w,w1.x,w1.y,w1.z,w1.w};
        s16x8 outv;
#pragma unroll
        for (int ii = 0; ii < 8; ++ii) outv[ii] = (short)f2b(r[ii] * scale * wf[ii]);
        *(s16x8*)&Ksh[j][d0] = outv;
    }
    // ---- V scatter (transposed, stride 162) ----
#pragma unroll
    for (int cch = 0; cch < 5; ++cch) {
        int w  = cch * 32 + (tid & 31);
        int d0 = (tid >> 5) * 8;
#pragma unroll
        for (int jj = 0; jj < 8; ++jj) Vt[d0 + jj][w] = ((const u16*)&vraw[cch])[jj];
    }
    // ---- Q rope + rms (in-register) ----
    s16x8 qf0, qf1;
    {
        const float* cp = cosT + t * 32 + g * 8;
        const float* sp = sinT + t * 32 + g * 8;
        float4 c0 = *(const float4*)(cp), c1 = *(const float4*)(cp + 4);
        float4 s0 = *(const float4*)(sp), s1 = *(const float4*)(sp + 4);
        float cf[8] = {c0.x,c0.y,c0.z,c0.w,c1.x,c1.y,c1.z,c1.w};
        float sf[8] = {s0.x,s0.y,s0.z,s0.w,s1.x,s1.y,s1.z,s1.w};
        float rl[8], rh[8]; float ssl = 0.f;
#pragma unroll
        for (int ii = 0; ii < 8; ++ii) {
            float ql = b2f((u16)q0r[ii]), qh = b2f((u16)q1r[ii]);
            rl[ii] = ql * cf[ii] - qh * sf[ii];
            rh[ii] = qh * cf[ii] + ql * sf[ii];
            ssl += rl[ii]*rl[ii] + rh[ii]*rh[ii];
        }
        ssl += __shfl_xor(ssl, 16);
        ssl += __shfl_xor(ssl, 32);
        float scale = rsqrtf(ssl * (1.0f / 64.0f) + 1e-6f);
        float4 wl0 = *(const float4*)(qw + g * 8), wl1 = *(const float4*)(qw + g * 8 + 4);
        float4 wh0 = *(const float4*)(qw + 32 + g * 8), wh1 = *(const float4*)(qw + 32 + g * 8 + 4);
        float wlo[8] = {wl0.x,wl0.y,wl0.z,wl0.w,wl1.x,wl1.y,wl1.z,wl1.w};
        float whi[8] = {wh0.x,wh0.y,wh0.z,wh0.w,wh1.x,wh1.y,wh1.z,wh1.w};
#pragma unroll
        for (int ii = 0; ii < 8; ++ii) {
            qf0[ii] = (short)f2b(rl[ii] * scale * wlo[ii]);
            qf1[ii] = (short)f2b(rh[ii] * scale * whi[ii]);
        }
    }
    __syncthreads();
    // ---- QK^T -> softmax -> PV (verified path) ----
    float s[9][4];
    float mx = -INFINITY;
    for (int wt = 0; wt < 9; ++wt) {
        int ldsrow = jb + wt * 16 + q;
        s16x8 kf0 = *(const s16x8*)&Ksh[ldsrow][g * 8];
        s16x8 kf1 = *(const s16x8*)&Ksh[ldsrow][32 + g * 8];
        f32x4 accv = {0, 0, 0, 0};
        accv = __builtin_amdgcn_mfma_f32_16x16x32_bf16(kf0, qf0, accv, 0, 0, 0);
        accv = __builtin_amdgcn_mfma_f32_16x16x32_bf16(kf1, qf1, accv, 0, 0, 0);
#pragma unroll
        for (int r = 0; r < 4; ++r) {
            int woff = wt * 16 + g * 4 + r;
            int key  = tw - 127 + woff;
            bool ok = (woff >= q) && (woff <= q + 127) && (key >= 0);
            float sv = ok ? accv[r] * 0.125f : -INFINITY;
            s[wt][r] = sv;
            mx = fmaxf(mx, sv);
        }
    }
    mx = fmaxf(mx, __shfl_xor(mx, 16));
    mx = fmaxf(mx, __shfl_xor(mx, 32));
    float sum = 0.f;
    s16x4 pb[9];
    for (int wt = 0; wt < 9; ++wt) {
#pragma unroll
        for (int r = 0; r < 4; ++r) {
            float p = __expf(s[wt][r] - mx);
            sum += p;
            pb[wt][r] = (short)f2b(p);
        }
    }
    sum += __shfl_xor(sum, 16);
    sum += __shfl_xor(sum, 32);
    float inv = 1.0f / sum;
    f32x4 oacc[4];
#pragma unroll
    for (int dt = 0; dt < 4; ++dt) {
        f32x4 a = {0, 0, 0, 0};
        for (int wt = 0; wt < 9; ++wt) {
            int col = jb + wt * 16 + g * 4;
            s16x4 vf = *(const s16x4*)&Vt[dt * 16 + q][col];
            a = __builtin_amdgcn_mfma_f32_16x16x16bf16_1k(vf, pb[wt], a, 0, 0, 0);
        }
        oacc[dt] = a;
    }
    __syncthreads();
    float (*Osh)[16][68] = (float (*)[16][68])&Ksh[0][0];
#pragma unroll
    for (int dt = 0; dt < 4; ++dt)
#pragma unroll
        for (int r = 0; r < 4; ++r)
            Osh[wv][q][dt * 16 + g * 4 + r] = oacc[dt][r] * inv;
    __syncthreads();
    const int qq = lane >> 2, dd0 = (lane & 3) * 16;
    const int r7 = qq & 7;
    u16* oprow = attb + (size_t)(tw + qq) * 512 + h * 64;
    s16x8 v0, v1;
#pragma unroll
    for (int j = 0; j < 8; ++j) v0[j] = (short)f2b(Osh[wv][qq][dd0 + j]);
#pragma unroll
    for (int j = 0; j < 8; ++j) v1[j] = (short)f2b(Osh[wv][qq][dd0 + 8 + j]);
    const int cc0 = (dd0 >> 3) ^ r7;
    const int cc1 = ((dd0 >> 3) + 1) ^ r7;
    *(s16x8*)(oprow + cc0 * 8) = v0;
    *(s16x8*)(oprow + cc1 * 8) = v1;
}

// ---------------------------------------------------------------------------
// Workspace: xb [2048*512 u16] | Wt [1024*512] | Wot [512*512] |
//            qkvb [2048*1024] | attb [2048*512]  ≈ 9.5 MB
// ---------------------------------------------------------------------------
extern "C" void kernel_launch(void* const* d_in, const int* in_sizes, int n_in,
                              void* d_out, int out_size, void* d_ws, size_t ws_size,
                              hipStream_t stream)
{
    const float* x    = (const float*)d_in[0];
    const float* Wq   = (const float*)d_in[1];
    const float* Wk   = (const float*)d_in[2];
    const float* Wv   = (const float*)d_in[3];
    const float* Wo   = (const float*)d_in[4];
    const float* qw   = (const float*)d_in[5];
    const float* kw   = (const float*)d_in[6];
    const float* cosT = (const float*)d_in[7];
    const float* sinT = (const float*)d_in[8];

    u16* ws   = (u16*)d_ws;
    u16* xb   = ws;                               // 2048*512
    u16* Wt   = xb   + (size_t)2048 * 512;        // 1024*512
    u16* Wot  = Wt   + (size_t)1024 * 512;        // 512*512
    u16* qkvb = Wot  + (size_t)512 * 512;         // 2048*1024
    u16* attb = qkvb + (size_t)2048 * 1024;       // 2048*512

    dim3 blk(256);
    hipLaunchKernelGGL(prep, dim3(704), blk, 0, stream, x, Wq, Wk, Wv, Wo, xb, Wt, Wot);
    hipLaunchKernelGGL((gemm_mfma<u16>), dim3(16, 32), blk, 0, stream, xb, Wt, qkvb, 1024);
    hipLaunchKernelGGL(swa_mfma, dim3(64, 4), blk, 0, stream,
                       qkvb, cosT, sinT, qw, kw, attb);
    hipLaunchKernelGGL((gemm_mfma<float>), dim3(8, 32), blk, 0, stream,
                       attb, Wot, (float*)d_out, 512);
}